// Round 1
// baseline (579.404 us; speedup 1.0000x reference)
//
#include <hip/hip_runtime.h>
#include <hip/hip_bf16.h>

#define EMB 256
#define NHEADS 8
#define DHEAD 32
#define SEQ 21760
#define NB 2
#define NROW (NB * SEQ)   // 43520
#define TM 32
#define LN_EPS 1e-5f

typedef __hip_bfloat16 bf16;

// ---------------- K1: V = mask ? 0 : (img_feat @ Wv + bv)  -> bf16 ----------
__global__ __launch_bounds__(256) void k_value(const float* __restrict__ A,
                                               const float* __restrict__ W,
                                               const float* __restrict__ bias,
                                               const unsigned char* __restrict__ mask,
                                               bf16* __restrict__ V) {
  __shared__ float As[TM * EMB];
  const int tid = threadIdx.x;
  const int row0 = blockIdx.x * TM;
  const float4* Ag = (const float4*)(A + (size_t)row0 * EMB);
  float4* As4 = (float4*)As;
#pragma unroll
  for (int j = 0; j < 8; ++j) As4[tid + j * 256] = Ag[tid + j * 256];
  __syncthreads();
  const int tcol = tid & 63, trow = tid >> 6;
  float acc[8][4];
#pragma unroll
  for (int r = 0; r < 8; ++r)
#pragma unroll
    for (int s = 0; s < 4; ++s) acc[r][s] = 0.f;
  for (int k4 = 0; k4 < 64; ++k4) {
    float4 a[8];
#pragma unroll
    for (int r = 0; r < 8; ++r) a[r] = As4[(trow * 8 + r) * 64 + k4];
#pragma unroll
    for (int i = 0; i < 4; ++i) {
      const int k = k4 * 4 + i;
      float wv[4];
#pragma unroll
      for (int s = 0; s < 4; ++s) wv[s] = W[k * EMB + tcol + 64 * s];
#pragma unroll
      for (int r = 0; r < 8; ++r) {
        const float av = (i == 0) ? a[r].x : (i == 1) ? a[r].y : (i == 2) ? a[r].z : a[r].w;
#pragma unroll
        for (int s = 0; s < 4; ++s) acc[r][s] = fmaf(av, wv[s], acc[r][s]);
      }
    }
  }
#pragma unroll
  for (int r = 0; r < 8; ++r) {
    const int row = row0 + trow * 8 + r;
    const bool m = mask[row] != 0;
#pragma unroll
    for (int s = 0; s < 4; ++s) {
      const int c = tcol + 64 * s;
      const float v = m ? 0.f : (acc[r][s] + bias[c]);
      V[(size_t)row * EMB + c] = __float2bfloat16(v);
    }
  }
}

// ---------------- K2: q = qf + qp; off = q@Woff + boff; lg = q@Wattn + battn -
__global__ __launch_bounds__(256) void k_offattn(const float* __restrict__ qf,
                                                 const float* __restrict__ qp,
                                                 const float* __restrict__ Woff,
                                                 const float* __restrict__ boff,
                                                 const float* __restrict__ Wattn,
                                                 const float* __restrict__ battn,
                                                 bf16* __restrict__ off,
                                                 bf16* __restrict__ lg) {
  __shared__ float As[TM * EMB];
  const int tid = threadIdx.x;
  const int row0 = blockIdx.x * TM;
  const float4* Af = (const float4*)(qf + (size_t)row0 * EMB);
  const float4* Ap = (const float4*)(qp + (size_t)row0 * EMB);
  float4* As4 = (float4*)As;
#pragma unroll
  for (int j = 0; j < 8; ++j) {
    const int ft = tid + j * 256;
    float4 a = Af[ft], b = Ap[ft], r;
    r.x = a.x + b.x; r.y = a.y + b.y; r.z = a.z + b.z; r.w = a.w + b.w;
    As4[ft] = r;
  }
  __syncthreads();
  const int tcol = tid & 63, trow = tid >> 6;
  float acc[8][6];
#pragma unroll
  for (int r = 0; r < 8; ++r)
#pragma unroll
    for (int s = 0; s < 6; ++s) acc[r][s] = 0.f;
  for (int k4 = 0; k4 < 64; ++k4) {
    float4 a[8];
#pragma unroll
    for (int r = 0; r < 8; ++r) a[r] = As4[(trow * 8 + r) * 64 + k4];
#pragma unroll
    for (int i = 0; i < 4; ++i) {
      const int k = k4 * 4 + i;
      float wv[6];
#pragma unroll
      for (int s = 0; s < 4; ++s) wv[s] = Woff[k * 256 + tcol + 64 * s];
#pragma unroll
      for (int s = 4; s < 6; ++s) wv[s] = Wattn[k * 128 + tcol + 64 * (s - 4)];
#pragma unroll
      for (int r = 0; r < 8; ++r) {
        const float av = (i == 0) ? a[r].x : (i == 1) ? a[r].y : (i == 2) ? a[r].z : a[r].w;
#pragma unroll
        for (int s = 0; s < 6; ++s) acc[r][s] = fmaf(av, wv[s], acc[r][s]);
      }
    }
  }
#pragma unroll
  for (int r = 0; r < 8; ++r) {
    const int row = row0 + trow * 8 + r;
#pragma unroll
    for (int s = 0; s < 4; ++s) {
      const int c = tcol + 64 * s;
      off[(size_t)row * 256 + c] = __float2bfloat16(acc[r][s] + boff[c]);
    }
#pragma unroll
    for (int s = 4; s < 6; ++s) {
      const int c = tcol + 64 * (s - 4);
      lg[(size_t)row * 128 + c] = __float2bfloat16(acc[r][s] + battn[c]);
    }
  }
}

// ---------------- K3: softmax + bilinear gather + attn-weighted sum ---------
__global__ __launch_bounds__(256) void k_sample(const bf16* __restrict__ V,
                                                const bf16* __restrict__ off,
                                                const bf16* __restrict__ lg,
                                                const float* __restrict__ qpts,
                                                const float* __restrict__ vratio,
                                                float* __restrict__ outb) {
  const int row = blockIdx.x;
  const int tid = threadIdx.x;
  const int b = row / SEQ;
  __shared__ float offs[256];
  __shared__ float lgs[128];
  __shared__ float scal[10];  // [0]=px [1]=py [2..9]=vratio(l,c)
  offs[tid] = __bfloat162float(off[(size_t)row * 256 + tid]);
  if (tid < 128) lgs[tid] = __bfloat162float(lg[(size_t)row * 128 + tid]);
  if (tid < 2) scal[tid] = qpts[(size_t)row * 2 + tid];
  if (tid >= 64 && tid < 72) scal[2 + tid - 64] = vratio[b * 8 + (tid - 64)];
  __syncthreads();
  const int h = tid >> 5;
  // softmax over the 16 (level,point) logits of this head
  float e[16];
  float m = -1e30f;
#pragma unroll
  for (int i = 0; i < 16; ++i) { e[i] = lgs[h * 16 + i]; m = fmaxf(m, e[i]); }
  float ssum = 0.f;
#pragma unroll
  for (int i = 0; i < 16; ++i) { e[i] = __expf(e[i] - m); ssum += e[i]; }
  const float inv = 1.f / ssum;

  const int Wl_[4] = {128, 64, 32, 16};
  const int st_[4] = {0, 16384, 20480, 21504};
  const float px = scal[0], py = scal[1];
  float out = 0.f;
#pragma unroll
  for (int l = 0; l < 4; ++l) {
    const int Wl = Wl_[l], Hl = Wl_[l], s0 = st_[l];
    const float fW = (float)Wl, fH = (float)Hl;
    const float rx = px * scal[2 + l * 2 + 0];
    const float ry = py * scal[2 + l * 2 + 1];
#pragma unroll
    for (int p = 0; p < 4; ++p) {
      const int oi = ((h * 4 + l) * 4 + p) * 2;
      const float locx = rx + offs[oi] / fW;
      const float locy = ry + offs[oi + 1] / fH;
      const float x = locx * fW - 0.5f;
      const float y = locy * fH - 0.5f;
      const float fx = floorf(x), fy = floorf(y);
      const float wx = x - fx, wy = y - fy;
      const int x0 = (int)fx, y0 = (int)fy;
      const int x1 = x0 + 1, y1 = y0 + 1;
      const int xc0 = min(max(x0, 0), Wl - 1), xc1 = min(max(x1, 0), Wl - 1);
      const int yc0 = min(max(y0, 0), Hl - 1), yc1 = min(max(y1, 0), Hl - 1);
      const float ox0 = (x0 >= 0 && x0 < Wl) ? 1.f : 0.f;
      const float ox1 = (x1 >= 0 && x1 < Wl) ? 1.f : 0.f;
      const float oy0 = (y0 >= 0 && y0 < Hl) ? 1.f : 0.f;
      const float oy1 = (y1 >= 0 && y1 < Hl) ? 1.f : 0.f;
      const float w00 = (1.f - wx) * (1.f - wy) * ox0 * oy0;
      const float w10 = wx * (1.f - wy) * ox1 * oy0;
      const float w01 = (1.f - wx) * wy * ox0 * oy1;
      const float w11 = wx * wy * ox1 * oy1;
      const size_t base = (size_t)(b * SEQ + s0) * 256 + tid;
      const float v00 = __bfloat162float(V[base + (size_t)(yc0 * Wl + xc0) * 256]);
      const float v10 = __bfloat162float(V[base + (size_t)(yc0 * Wl + xc1) * 256]);
      const float v01 = __bfloat162float(V[base + (size_t)(yc1 * Wl + xc0) * 256]);
      const float v11 = __bfloat162float(V[base + (size_t)(yc1 * Wl + xc1) * 256]);
      const float samp = w00 * v00 + w10 * v10 + w01 * v01 + w11 * v11;
      out = fmaf(e[l * 4 + p] * inv, samp, out);
    }
  }
  outb[(size_t)row * 256 + tid] = out;
}

// ---------------- K4: update = outb @ Wout + bout; LN(qf + update) ----------
__global__ __launch_bounds__(256) void k_outln(const float* __restrict__ outb,
                                               const float* __restrict__ W,
                                               const float* __restrict__ bias,
                                               const float* __restrict__ qf,
                                               const float* __restrict__ gamma,
                                               const float* __restrict__ beta,
                                               float* __restrict__ y) {
  __shared__ float As[TM * EMB];  // A tile, reused as x tile for LN
  const int tid = threadIdx.x;
  const int row0 = blockIdx.x * TM;
  const float4* Ag = (const float4*)(outb + (size_t)row0 * EMB);
  float4* As4 = (float4*)As;
#pragma unroll
  for (int j = 0; j < 8; ++j) As4[tid + j * 256] = Ag[tid + j * 256];
  __syncthreads();
  const int tcol = tid & 63, trow = tid >> 6;
  float acc[8][4];
#pragma unroll
  for (int r = 0; r < 8; ++r)
#pragma unroll
    for (int s = 0; s < 4; ++s) acc[r][s] = 0.f;
  for (int k4 = 0; k4 < 64; ++k4) {
    float4 a[8];
#pragma unroll
    for (int r = 0; r < 8; ++r) a[r] = As4[(trow * 8 + r) * 64 + k4];
#pragma unroll
    for (int i = 0; i < 4; ++i) {
      const int k = k4 * 4 + i;
      float wv[4];
#pragma unroll
      for (int s = 0; s < 4; ++s) wv[s] = W[k * EMB + tcol + 64 * s];
#pragma unroll
      for (int r = 0; r < 8; ++r) {
        const float av = (i == 0) ? a[r].x : (i == 1) ? a[r].y : (i == 2) ? a[r].z : a[r].w;
#pragma unroll
        for (int s = 0; s < 4; ++s) acc[r][s] = fmaf(av, wv[s], acc[r][s]);
      }
    }
  }
  __syncthreads();  // everyone done reading A tile; reuse As as x tile
#pragma unroll
  for (int r = 0; r < 8; ++r) {
    const int row = row0 + trow * 8 + r;
#pragma unroll
    for (int s = 0; s < 4; ++s) {
      const int c = tcol + 64 * s;
      As[(trow * 8 + r) * 256 + c] = acc[r][s] + bias[c] + qf[(size_t)row * 256 + c];
    }
  }
  __syncthreads();
  const int lane = tid & 63, wv = tid >> 6;
#pragma unroll
  for (int rr = 0; rr < 8; ++rr) {
    const int r = wv * 8 + rr;
    float s1 = 0.f, s2 = 0.f;
#pragma unroll
    for (int i = 0; i < 4; ++i) {
      const float xv = As[r * 256 + lane + 64 * i];
      s1 += xv; s2 += xv * xv;
    }
#pragma unroll
    for (int o = 32; o >= 1; o >>= 1) {
      s1 += __shfl_xor(s1, o);
      s2 += __shfl_xor(s2, o);
    }
    const float mu = s1 * (1.f / 256.f);
    const float var = s2 * (1.f / 256.f) - mu * mu;
    const float rsig = rsqrtf(var + LN_EPS);
#pragma unroll
    for (int i = 0; i < 4; ++i) {
      const int c = lane + 64 * i;
      const float xv = As[r * 256 + c];
      y[(size_t)(row0 + r) * 256 + c] = (xv - mu) * rsig * gamma[c] + beta[c];
    }
  }
}

extern "C" void kernel_launch(void* const* d_in, const int* in_sizes, int n_in,
                              void* d_out, int out_size, void* d_ws, size_t ws_size,
                              hipStream_t stream) {
  const float* img_feat = (const float*)d_in[0];
  // d_in[1] = img_shapes (hardcoded: (128,128),(64,64),(32,32),(16,16))
  const unsigned char* img_mask = (const unsigned char*)d_in[2];
  const float* vratio = (const float*)d_in[3];
  const float* qf = (const float*)d_in[4];
  const float* qp = (const float*)d_in[5];
  const float* qpts = (const float*)d_in[6];
  const float* Wv = (const float*)d_in[7];
  const float* bv = (const float*)d_in[8];
  const float* Woff = (const float*)d_in[9];
  const float* boff = (const float*)d_in[10];
  const float* Wattn = (const float*)d_in[11];
  const float* battn = (const float*)d_in[12];
  const float* Wout = (const float*)d_in[13];
  const float* bout = (const float*)d_in[14];
  const float* gamma = (const float*)d_in[15];
  const float* beta = (const float*)d_in[16];

  char* ws = (char*)d_ws;
  bf16* V = (bf16*)ws;                                       // NROW*256 bf16
  bf16* off = (bf16*)(ws + (size_t)NROW * 256 * 2);          // NROW*256 bf16
  bf16* lg = (bf16*)(ws + (size_t)NROW * 256 * 4);           // NROW*128 bf16
  float* outb = (float*)d_out;  // reuse d_out as sampled-out scratch

  dim3 blk(256);
  k_value<<<NROW / TM, blk, 0, stream>>>(img_feat, Wv, bv, img_mask, V);
  k_offattn<<<NROW / TM, blk, 0, stream>>>(qf, qp, Woff, boff, Wattn, battn, off, lg);
  k_sample<<<NROW, blk, 0, stream>>>(V, off, lg, qpts, vratio, outb);
  k_outln<<<NROW / TM, blk, 0, stream>>>(outb, Wout, bout, qf, gamma, beta, (float*)d_out);
}

// Round 2
// 414.427 us; speedup vs baseline: 1.3981x; 1.3981x over previous
//
#include <hip/hip_runtime.h>
#include <hip/hip_bf16.h>

#define EMB 256
#define NHEADS 8
#define DHEAD 32
#define SEQ 21760
#define NB 2
#define NROW (NB * SEQ)   // 43520
#define TM 32
#define QB 4              // queries per k_sample block
#define LN_EPS 1e-5f

typedef __hip_bfloat16 bf16;

__device__ __forceinline__ float bflo(unsigned int u) {
  return __uint_as_float(u << 16);
}
__device__ __forceinline__ float bfhi(unsigned int u) {
  return __uint_as_float(u & 0xffff0000u);
}

// ---------------- K1: V = mask ? 0 : (img_feat @ Wv + bv)  -> bf16 ----------
__global__ __launch_bounds__(256) void k_value(const float* __restrict__ A,
                                               const float* __restrict__ W,
                                               const float* __restrict__ bias,
                                               const unsigned char* __restrict__ mask,
                                               bf16* __restrict__ V) {
  __shared__ float As[TM * EMB];
  const int tid = threadIdx.x;
  const int row0 = blockIdx.x * TM;
  const float4* Ag = (const float4*)(A + (size_t)row0 * EMB);
  float4* As4 = (float4*)As;
#pragma unroll
  for (int j = 0; j < 8; ++j) As4[tid + j * 256] = Ag[tid + j * 256];
  __syncthreads();
  const int tcol = tid & 63, trow = tid >> 6;
  float acc[8][4];
#pragma unroll
  for (int r = 0; r < 8; ++r)
#pragma unroll
    for (int s = 0; s < 4; ++s) acc[r][s] = 0.f;
  for (int k4 = 0; k4 < 64; ++k4) {
    float4 a[8];
#pragma unroll
    for (int r = 0; r < 8; ++r) a[r] = As4[(trow * 8 + r) * 64 + k4];
#pragma unroll
    for (int i = 0; i < 4; ++i) {
      const int k = k4 * 4 + i;
      float wv[4];
#pragma unroll
      for (int s = 0; s < 4; ++s) wv[s] = W[k * EMB + tcol + 64 * s];
#pragma unroll
      for (int r = 0; r < 8; ++r) {
        const float av = (i == 0) ? a[r].x : (i == 1) ? a[r].y : (i == 2) ? a[r].z : a[r].w;
#pragma unroll
        for (int s = 0; s < 4; ++s) acc[r][s] = fmaf(av, wv[s], acc[r][s]);
      }
    }
  }
#pragma unroll
  for (int r = 0; r < 8; ++r) {
    const int row = row0 + trow * 8 + r;
    const bool m = mask[row] != 0;
#pragma unroll
    for (int s = 0; s < 4; ++s) {
      const int c = tcol + 64 * s;
      const float v = m ? 0.f : (acc[r][s] + bias[c]);
      V[(size_t)row * EMB + c] = __float2bfloat16(v);
    }
  }
}

// ---------------- K2: q = qf + qp; off = q@Woff + boff; lg = q@Wattn + battn -
__global__ __launch_bounds__(256) void k_offattn(const float* __restrict__ qf,
                                                 const float* __restrict__ qp,
                                                 const float* __restrict__ Woff,
                                                 const float* __restrict__ boff,
                                                 const float* __restrict__ Wattn,
                                                 const float* __restrict__ battn,
                                                 bf16* __restrict__ off,
                                                 bf16* __restrict__ lg) {
  __shared__ float As[TM * EMB];
  const int tid = threadIdx.x;
  const int row0 = blockIdx.x * TM;
  const float4* Af = (const float4*)(qf + (size_t)row0 * EMB);
  const float4* Ap = (const float4*)(qp + (size_t)row0 * EMB);
  float4* As4 = (float4*)As;
#pragma unroll
  for (int j = 0; j < 8; ++j) {
    const int ft = tid + j * 256;
    float4 a = Af[ft], b = Ap[ft], r;
    r.x = a.x + b.x; r.y = a.y + b.y; r.z = a.z + b.z; r.w = a.w + b.w;
    As4[ft] = r;
  }
  __syncthreads();
  const int tcol = tid & 63, trow = tid >> 6;
  float acc[8][6];
#pragma unroll
  for (int r = 0; r < 8; ++r)
#pragma unroll
    for (int s = 0; s < 6; ++s) acc[r][s] = 0.f;
  for (int k4 = 0; k4 < 64; ++k4) {
    float4 a[8];
#pragma unroll
    for (int r = 0; r < 8; ++r) a[r] = As4[(trow * 8 + r) * 64 + k4];
#pragma unroll
    for (int i = 0; i < 4; ++i) {
      const int k = k4 * 4 + i;
      float wv[6];
#pragma unroll
      for (int s = 0; s < 4; ++s) wv[s] = Woff[k * 256 + tcol + 64 * s];
#pragma unroll
      for (int s = 4; s < 6; ++s) wv[s] = Wattn[k * 128 + tcol + 64 * (s - 4)];
#pragma unroll
      for (int r = 0; r < 8; ++r) {
        const float av = (i == 0) ? a[r].x : (i == 1) ? a[r].y : (i == 2) ? a[r].z : a[r].w;
#pragma unroll
        for (int s = 0; s < 6; ++s) acc[r][s] = fmaf(av, wv[s], acc[r][s]);
      }
    }
  }
#pragma unroll
  for (int r = 0; r < 8; ++r) {
    const int row = row0 + trow * 8 + r;
#pragma unroll
    for (int s = 0; s < 4; ++s) {
      const int c = tcol + 64 * s;
      off[(size_t)row * 256 + c] = __float2bfloat16(acc[r][s] + boff[c]);
    }
#pragma unroll
    for (int s = 4; s < 6; ++s) {
      const int c = tcol + 64 * (s - 4);
      lg[(size_t)row * 128 + c] = __float2bfloat16(acc[r][s] + battn[c]);
    }
  }
}

// ---------------- K3: softmax + bilinear gather + attn-weighted sum ---------
// Block = QB queries. Phase 0: per-(q,head) softmax stats (32 threads).
// Phase 1: 512 sample tasks compute 4 corner indices + 4 premultiplied weights.
// Phase 2: thread = (q, head, 4 channels) does pure gather+fma.
__global__ __launch_bounds__(256) void k_sample(const bf16* __restrict__ V,
                                                const bf16* __restrict__ off,
                                                const bf16* __restrict__ lg,
                                                const float* __restrict__ qpts,
                                                const float* __restrict__ vratio,
                                                float* __restrict__ outb) {
  __shared__ int4 sIdx[QB * 16 * 8];   // [q][i][h]
  __shared__ float4 sW[QB * 16 * 8];
  __shared__ float sMax[QB * 8], sInv[QB * 8];
  const int t = threadIdx.x;
  const int row0 = blockIdx.x * QB;

  // ---- phase 0: softmax stats per (q, head)
  if (t < QB * 8) {
    const int q = t >> 3, h = t & 7;
    const int row = row0 + q;
    const uint4* lp = (const uint4*)(lg + (size_t)row * 128 + h * 16);
    uint4 u0 = lp[0], u1 = lp[1];
    float v[16];
    v[0] = bflo(u0.x); v[1] = bfhi(u0.x); v[2] = bflo(u0.y); v[3] = bfhi(u0.y);
    v[4] = bflo(u0.z); v[5] = bfhi(u0.z); v[6] = bflo(u0.w); v[7] = bfhi(u0.w);
    v[8] = bflo(u1.x); v[9] = bfhi(u1.x); v[10] = bflo(u1.y); v[11] = bfhi(u1.y);
    v[12] = bflo(u1.z); v[13] = bfhi(u1.z); v[14] = bflo(u1.w); v[15] = bfhi(u1.w);
    float m = v[0];
#pragma unroll
    for (int i = 1; i < 16; ++i) m = fmaxf(m, v[i]);
    float s = 0.f;
#pragma unroll
    for (int i = 0; i < 16; ++i) s += __expf(v[i] - m);
    sMax[t] = m;
    sInv[t] = 1.f / s;
  }
  __syncthreads();

  // ---- phase 1: per-sample geometry, 2 tasks per thread
  const int Wl_[4] = {128, 64, 32, 16};
  const int st_[4] = {0, 16384, 20480, 21504};
#pragma unroll
  for (int tt = 0; tt < 2; ++tt) {
    const int sid = t + tt * 256;
    const int q = sid >> 7, s = sid & 127;
    const int h = s >> 4, i = s & 15, l = i >> 2;
    const int row = row0 + q;
    const int b = row >= SEQ;  // NB == 2
    const unsigned int u = *(const unsigned int*)(off + (size_t)row * 256 + s * 2);
    const float ox = bflo(u), oy = bfhi(u);
    const float lgv = bflo(*(const unsigned short*)(lg + (size_t)row * 128 + s) << 16);
    const float e = __expf(lgv - sMax[q * 8 + h]) * sInv[q * 8 + h];
    const float px = qpts[(size_t)row * 2], py = qpts[(size_t)row * 2 + 1];
    const float vrx = vratio[b * 8 + l * 2], vry = vratio[b * 8 + l * 2 + 1];
    const int Wl = Wl_[l];
    const float fW = (float)Wl;
    // x = (px*vrx + ox/W)*W - 0.5  ==  px*vrx*W + ox - 0.5 (fp-equiv within ulp)
    const float x = fmaf(px * vrx, fW, ox) - 0.5f;
    const float y = fmaf(py * vry, fW, oy) - 0.5f;
    const float fx = floorf(x), fy = floorf(y);
    const float wx = x - fx, wy = y - fy;
    const int x0 = (int)fx, y0 = (int)fy;
    const int x1 = x0 + 1, y1 = y0 + 1;
    const int xc0 = min(max(x0, 0), Wl - 1), xc1 = min(max(x1, 0), Wl - 1);
    const int yc0 = min(max(y0, 0), Wl - 1), yc1 = min(max(y1, 0), Wl - 1);
    const float ox0 = (x0 >= 0 && x0 < Wl) ? e : 0.f;   // fold attn weight in
    const float ox1 = (x1 >= 0 && x1 < Wl) ? e : 0.f;
    const float oy0 = (y0 >= 0 && y0 < Wl) ? 1.f : 0.f;
    const float oy1 = (y1 >= 0 && y1 < Wl) ? 1.f : 0.f;
    const int base = b * SEQ + st_[l];
    const int r0 = base + yc0 * Wl, r1 = base + yc1 * Wl;
    sIdx[(q * 16 + i) * 8 + h] = make_int4(r0 + xc0, r0 + xc1, r1 + xc0, r1 + xc1);
    sW[(q * 16 + i) * 8 + h] =
        make_float4((1.f - wx) * (1.f - wy) * ox0 * oy0, wx * (1.f - wy) * ox1 * oy0,
                    (1.f - wx) * wy * ox0 * oy1, wx * wy * ox1 * oy1);
  }
  __syncthreads();

  // ---- phase 2: gather + weighted accumulate; thread = (q, h, 4 channels)
  const int q = t >> 6, sub = t & 63;
  const int h = sub >> 3, dg = sub & 7;
  const int row = row0 + q;
  const bf16* vb = V + h * 32 + dg * 4;
  float a0 = 0.f, a1 = 0.f, a2 = 0.f, a3 = 0.f;
#pragma unroll
  for (int i = 0; i < 16; ++i) {
    const int4 idx = sIdx[(q * 16 + i) * 8 + h];
    const float4 w = sW[(q * 16 + i) * 8 + h];
    {
      const uint2 u = *(const uint2*)(vb + (size_t)idx.x * 256);
      a0 = fmaf(w.x, bflo(u.x), a0); a1 = fmaf(w.x, bfhi(u.x), a1);
      a2 = fmaf(w.x, bflo(u.y), a2); a3 = fmaf(w.x, bfhi(u.y), a3);
    }
    {
      const uint2 u = *(const uint2*)(vb + (size_t)idx.y * 256);
      a0 = fmaf(w.y, bflo(u.x), a0); a1 = fmaf(w.y, bfhi(u.x), a1);
      a2 = fmaf(w.y, bflo(u.y), a2); a3 = fmaf(w.y, bfhi(u.y), a3);
    }
    {
      const uint2 u = *(const uint2*)(vb + (size_t)idx.z * 256);
      a0 = fmaf(w.z, bflo(u.x), a0); a1 = fmaf(w.z, bfhi(u.x), a1);
      a2 = fmaf(w.z, bflo(u.y), a2); a3 = fmaf(w.z, bfhi(u.y), a3);
    }
    {
      const uint2 u = *(const uint2*)(vb + (size_t)idx.w * 256);
      a0 = fmaf(w.w, bflo(u.x), a0); a1 = fmaf(w.w, bfhi(u.x), a1);
      a2 = fmaf(w.w, bflo(u.y), a2); a3 = fmaf(w.w, bfhi(u.y), a3);
    }
  }
  float4 o; o.x = a0; o.y = a1; o.z = a2; o.w = a3;
  *(float4*)(outb + (size_t)row * 256 + h * 32 + dg * 4) = o;
}

// ---------------- K4: update = outb @ Wout + bout; LN(qf + update) ----------
__global__ __launch_bounds__(256) void k_outln(const float* __restrict__ outb,
                                               const float* __restrict__ W,
                                               const float* __restrict__ bias,
                                               const float* __restrict__ qf,
                                               const float* __restrict__ gamma,
                                               const float* __restrict__ beta,
                                               float* __restrict__ y) {
  __shared__ float As[TM * EMB];  // A tile, reused as x tile for LN
  const int tid = threadIdx.x;
  const int row0 = blockIdx.x * TM;
  const float4* Ag = (const float4*)(outb + (size_t)row0 * EMB);
  float4* As4 = (float4*)As;
#pragma unroll
  for (int j = 0; j < 8; ++j) As4[tid + j * 256] = Ag[tid + j * 256];
  __syncthreads();
  const int tcol = tid & 63, trow = tid >> 6;
  float acc[8][4];
#pragma unroll
  for (int r = 0; r < 8; ++r)
#pragma unroll
    for (int s = 0; s < 4; ++s) acc[r][s] = 0.f;
  for (int k4 = 0; k4 < 64; ++k4) {
    float4 a[8];
#pragma unroll
    for (int r = 0; r < 8; ++r) a[r] = As4[(trow * 8 + r) * 64 + k4];
#pragma unroll
    for (int i = 0; i < 4; ++i) {
      const int k = k4 * 4 + i;
      float wv[4];
#pragma unroll
      for (int s = 0; s < 4; ++s) wv[s] = W[k * EMB + tcol + 64 * s];
#pragma unroll
      for (int r = 0; r < 8; ++r) {
        const float av = (i == 0) ? a[r].x : (i == 1) ? a[r].y : (i == 2) ? a[r].z : a[r].w;
#pragma unroll
        for (int s = 0; s < 4; ++s) acc[r][s] = fmaf(av, wv[s], acc[r][s]);
      }
    }
  }
  __syncthreads();  // everyone done reading A tile; reuse As as x tile
#pragma unroll
  for (int r = 0; r < 8; ++r) {
    const int row = row0 + trow * 8 + r;
#pragma unroll
    for (int s = 0; s < 4; ++s) {
      const int c = tcol + 64 * s;
      As[(trow * 8 + r) * 256 + c] = acc[r][s] + bias[c] + qf[(size_t)row * 256 + c];
    }
  }
  __syncthreads();
  const int lane = tid & 63, wv = tid >> 6;
#pragma unroll
  for (int rr = 0; rr < 8; ++rr) {
    const int r = wv * 8 + rr;
    float s1 = 0.f, s2 = 0.f;
#pragma unroll
    for (int i = 0; i < 4; ++i) {
      const float xv = As[r * 256 + lane + 64 * i];
      s1 += xv; s2 += xv * xv;
    }
#pragma unroll
    for (int o = 32; o >= 1; o >>= 1) {
      s1 += __shfl_xor(s1, o);
      s2 += __shfl_xor(s2, o);
    }
    const float mu = s1 * (1.f / 256.f);
    const float var = s2 * (1.f / 256.f) - mu * mu;
    const float rsig = rsqrtf(var + LN_EPS);
#pragma unroll
    for (int i = 0; i < 4; ++i) {
      const int c = lane + 64 * i;
      const float xv = As[r * 256 + c];
      y[(size_t)(row0 + r) * 256 + c] = (xv - mu) * rsig * gamma[c] + beta[c];
    }
  }
}

extern "C" void kernel_launch(void* const* d_in, const int* in_sizes, int n_in,
                              void* d_out, int out_size, void* d_ws, size_t ws_size,
                              hipStream_t stream) {
  const float* img_feat = (const float*)d_in[0];
  // d_in[1] = img_shapes (hardcoded: (128,128),(64,64),(32,32),(16,16))
  const unsigned char* img_mask = (const unsigned char*)d_in[2];
  const float* vratio = (const float*)d_in[3];
  const float* qf = (const float*)d_in[4];
  const float* qp = (const float*)d_in[5];
  const float* qpts = (const float*)d_in[6];
  const float* Wv = (const float*)d_in[7];
  const float* bv = (const float*)d_in[8];
  const float* Woff = (const float*)d_in[9];
  const float* boff = (const float*)d_in[10];
  const float* Wattn = (const float*)d_in[11];
  const float* battn = (const float*)d_in[12];
  const float* Wout = (const float*)d_in[13];
  const float* bout = (const float*)d_in[14];
  const float* gamma = (const float*)d_in[15];
  const float* beta = (const float*)d_in[16];

  char* ws = (char*)d_ws;
  bf16* V = (bf16*)ws;                                       // NROW*256 bf16
  bf16* off = (bf16*)(ws + (size_t)NROW * 256 * 2);          // NROW*256 bf16
  bf16* lg = (bf16*)(ws + (size_t)NROW * 256 * 4);           // NROW*128 bf16
  float* outb = (float*)d_out;  // reuse d_out as sampled-out scratch

  dim3 blk(256);
  k_value<<<NROW / TM, blk, 0, stream>>>(img_feat, Wv, bv, img_mask, V);
  k_offattn<<<NROW / TM, blk, 0, stream>>>(qf, qp, Woff, boff, Wattn, battn, off, lg);
  k_sample<<<NROW / QB, blk, 0, stream>>>(V, off, lg, qpts, vratio, outb);
  k_outln<<<NROW / TM, blk, 0, stream>>>(outb, Wout, bout, qf, gamma, beta, (float*)d_out);
}

// Round 7
// 414.365 us; speedup vs baseline: 1.3983x; 1.0001x over previous
//
#include <hip/hip_runtime.h>
#include <hip/hip_bf16.h>

#define EMB 256
#define NHEADS 8
#define DHEAD 32
#define SEQ 21760
#define NB 2
#define NROW (NB * SEQ)   // 43520
#define TM 32
#define QB 4              // queries per k_sample block
#define LN_EPS 1e-5f

typedef __hip_bfloat16 bf16;

__device__ __forceinline__ float bflo(unsigned int u) {
  return __uint_as_float(u << 16);
}
__device__ __forceinline__ float bfhi(unsigned int u) {
  return __uint_as_float(u & 0xffff0000u);
}
__device__ __forceinline__ float bf2f(unsigned short u) {
  return __uint_as_float((unsigned int)u << 16);
}

// ---------------- K1: V = mask ? 0 : (img_feat @ Wv + bv)  -> bf16 ----------
__global__ __launch_bounds__(256) void k_value(const float* __restrict__ A,
                                               const float* __restrict__ W,
                                               const float* __restrict__ bias,
                                               const unsigned char* __restrict__ mask,
                                               bf16* __restrict__ V) {
  __shared__ float As[TM * EMB];
  const int tid = threadIdx.x;
  const int row0 = blockIdx.x * TM;
  const float4* Ag = (const float4*)(A + (size_t)row0 * EMB);
  float4* As4 = (float4*)As;
#pragma unroll
  for (int j = 0; j < 8; ++j) As4[tid + j * 256] = Ag[tid + j * 256];
  __syncthreads();
  const int tcol = tid & 63, trow = tid >> 6;
  float acc[8][4];
#pragma unroll
  for (int r = 0; r < 8; ++r)
#pragma unroll
    for (int s = 0; s < 4; ++s) acc[r][s] = 0.f;
  for (int k4 = 0; k4 < 64; ++k4) {
    float4 a[8];
#pragma unroll
    for (int r = 0; r < 8; ++r) a[r] = As4[(trow * 8 + r) * 64 + k4];
#pragma unroll
    for (int i = 0; i < 4; ++i) {
      const int k = k4 * 4 + i;
      float wv[4];
#pragma unroll
      for (int s = 0; s < 4; ++s) wv[s] = W[k * EMB + tcol + 64 * s];
#pragma unroll
      for (int r = 0; r < 8; ++r) {
        const float av = (i == 0) ? a[r].x : (i == 1) ? a[r].y : (i == 2) ? a[r].z : a[r].w;
#pragma unroll
        for (int s = 0; s < 4; ++s) acc[r][s] = fmaf(av, wv[s], acc[r][s]);
      }
    }
  }
#pragma unroll
  for (int r = 0; r < 8; ++r) {
    const int row = row0 + trow * 8 + r;
    const bool m = mask[row] != 0;
#pragma unroll
    for (int s = 0; s < 4; ++s) {
      const int c = tcol + 64 * s;
      const float v = m ? 0.f : (acc[r][s] + bias[c]);
      V[(size_t)row * EMB + c] = __float2bfloat16(v);
    }
  }
}

// ---------------- K2: q = qf + qp; off = q@Woff + boff; lg = q@Wattn + battn -
__global__ __launch_bounds__(256) void k_offattn(const float* __restrict__ qf,
                                                 const float* __restrict__ qp,
                                                 const float* __restrict__ Woff,
                                                 const float* __restrict__ boff,
                                                 const float* __restrict__ Wattn,
                                                 const float* __restrict__ battn,
                                                 bf16* __restrict__ off,
                                                 bf16* __restrict__ lg) {
  __shared__ float As[TM * EMB];
  const int tid = threadIdx.x;
  const int row0 = blockIdx.x * TM;
  const float4* Af = (const float4*)(qf + (size_t)row0 * EMB);
  const float4* Ap = (const float4*)(qp + (size_t)row0 * EMB);
  float4* As4 = (float4*)As;
#pragma unroll
  for (int j = 0; j < 8; ++j) {
    const int ft = tid + j * 256;
    float4 a = Af[ft], b = Ap[ft], r;
    r.x = a.x + b.x; r.y = a.y + b.y; r.z = a.z + b.z; r.w = a.w + b.w;
    As4[ft] = r;
  }
  __syncthreads();
  const int tcol = tid & 63, trow = tid >> 6;
  float acc[8][6];
#pragma unroll
  for (int r = 0; r < 8; ++r)
#pragma unroll
    for (int s = 0; s < 6; ++s) acc[r][s] = 0.f;
  for (int k4 = 0; k4 < 64; ++k4) {
    float4 a[8];
#pragma unroll
    for (int r = 0; r < 8; ++r) a[r] = As4[(trow * 8 + r) * 64 + k4];
#pragma unroll
    for (int i = 0; i < 4; ++i) {
      const int k = k4 * 4 + i;
      float wv[6];
#pragma unroll
      for (int s = 0; s < 4; ++s) wv[s] = Woff[k * 256 + tcol + 64 * s];
#pragma unroll
      for (int s = 4; s < 6; ++s) wv[s] = Wattn[k * 128 + tcol + 64 * (s - 4)];
#pragma unroll
      for (int r = 0; r < 8; ++r) {
        const float av = (i == 0) ? a[r].x : (i == 1) ? a[r].y : (i == 2) ? a[r].z : a[r].w;
#pragma unroll
        for (int s = 0; s < 6; ++s) acc[r][s] = fmaf(av, wv[s], acc[r][s]);
      }
    }
  }
#pragma unroll
  for (int r = 0; r < 8; ++r) {
    const int row = row0 + trow * 8 + r;
#pragma unroll
    for (int s = 0; s < 4; ++s) {
      const int c = tcol + 64 * s;
      off[(size_t)row * 256 + c] = __float2bfloat16(acc[r][s] + boff[c]);
    }
#pragma unroll
    for (int s = 4; s < 6; ++s) {
      const int c = tcol + 64 * (s - 4);
      lg[(size_t)row * 128 + c] = __float2bfloat16(acc[r][s] + battn[c]);
    }
  }
}

// ---------------- K3: softmax + bilinear gather + attn-weighted sum ---------
// Block = QB queries. Phase 0: per-(q,head) softmax stats (32 threads).
// Phase 1: 512 sample tasks compute 4 corner indices + 4 premultiplied weights.
// Phase 2: thread = (q, head, 4 channels) does pure gather+fma.
__global__ __launch_bounds__(256) void k_sample(const bf16* __restrict__ V,
                                                const bf16* __restrict__ off,
                                                const bf16* __restrict__ lg,
                                                const float* __restrict__ qpts,
                                                const float* __restrict__ vratio,
                                                float* __restrict__ outb) {
  __shared__ int4 sIdx[QB * 16 * 8];   // [q][i][h]
  __shared__ float4 sW[QB * 16 * 8];
  __shared__ float sMax[QB * 8], sInv[QB * 8];
  const int t = threadIdx.x;
  const int row0 = blockIdx.x * QB;

  // ---- phase 0: softmax stats per (q, head)
  if (t < QB * 8) {
    const int q = t >> 3, h = t & 7;
    const int row = row0 + q;
    const uint4* lp = (const uint4*)(lg + (size_t)row * 128 + h * 16);
    uint4 u0 = lp[0], u1 = lp[1];
    float v[16];
    v[0] = bflo(u0.x); v[1] = bfhi(u0.x); v[2] = bflo(u0.y); v[3] = bfhi(u0.y);
    v[4] = bflo(u0.z); v[5] = bfhi(u0.z); v[6] = bflo(u0.w); v[7] = bfhi(u0.w);
    v[8] = bflo(u1.x); v[9] = bfhi(u1.x); v[10] = bflo(u1.y); v[11] = bfhi(u1.y);
    v[12] = bflo(u1.z); v[13] = bfhi(u1.z); v[14] = bflo(u1.w); v[15] = bfhi(u1.w);
    float m = v[0];
#pragma unroll
    for (int i = 1; i < 16; ++i) m = fmaxf(m, v[i]);
    float s = 0.f;
#pragma unroll
    for (int i = 0; i < 16; ++i) s += __expf(v[i] - m);
    sMax[t] = m;
    sInv[t] = 1.f / s;
  }
  __syncthreads();

  // ---- phase 1: per-sample geometry, 2 tasks per thread
  const int Wl_[4] = {128, 64, 32, 16};
  const int st_[4] = {0, 16384, 20480, 21504};
#pragma unroll
  for (int tt = 0; tt < 2; ++tt) {
    const int sid = t + tt * 256;
    const int q = sid >> 7, s = sid & 127;
    const int h = s >> 4, i = s & 15, l = i >> 2;
    const int row = row0 + q;
    const int b = row >= SEQ;  // NB == 2
    const unsigned int u = *(const unsigned int*)(off + (size_t)row * 256 + s * 2);
    const float ox = bflo(u), oy = bfhi(u);
    // FIX (round 7): was bflo(ushort << 16) == double shift -> lgv was always 0
    const float lgv = bf2f(*(const unsigned short*)(lg + (size_t)row * 128 + s));
    const float e = __expf(lgv - sMax[q * 8 + h]) * sInv[q * 8 + h];
    const float px = qpts[(size_t)row * 2], py = qpts[(size_t)row * 2 + 1];
    const float vrx = vratio[b * 8 + l * 2], vry = vratio[b * 8 + l * 2 + 1];
    const int Wl = Wl_[l];
    const float fW = (float)Wl;
    // x = (px*vrx + ox/W)*W - 0.5  ==  px*vrx*W + ox - 0.5 (fp-equiv within ulp)
    const float x = fmaf(px * vrx, fW, ox) - 0.5f;
    const float y = fmaf(py * vry, fW, oy) - 0.5f;
    const float fx = floorf(x), fy = floorf(y);
    const float wx = x - fx, wy = y - fy;
    const int x0 = (int)fx, y0 = (int)fy;
    const int x1 = x0 + 1, y1 = y0 + 1;
    const int xc0 = min(max(x0, 0), Wl - 1), xc1 = min(max(x1, 0), Wl - 1);
    const int yc0 = min(max(y0, 0), Wl - 1), yc1 = min(max(y1, 0), Wl - 1);
    const float ox0 = (x0 >= 0 && x0 < Wl) ? e : 0.f;   // fold attn weight in
    const float ox1 = (x1 >= 0 && x1 < Wl) ? e : 0.f;
    const float oy0 = (y0 >= 0 && y0 < Wl) ? 1.f : 0.f;
    const float oy1 = (y1 >= 0 && y1 < Wl) ? 1.f : 0.f;
    const int base = b * SEQ + st_[l];
    const int r0 = base + yc0 * Wl, r1 = base + yc1 * Wl;
    sIdx[(q * 16 + i) * 8 + h] = make_int4(r0 + xc0, r0 + xc1, r1 + xc0, r1 + xc1);
    sW[(q * 16 + i) * 8 + h] =
        make_float4((1.f - wx) * (1.f - wy) * ox0 * oy0, wx * (1.f - wy) * ox1 * oy0,
                    (1.f - wx) * wy * ox0 * oy1, wx * wy * ox1 * oy1);
  }
  __syncthreads();

  // ---- phase 2: gather + weighted accumulate; thread = (q, h, 4 channels)
  const int q = t >> 6, sub = t & 63;
  const int h = sub >> 3, dg = sub & 7;
  const int row = row0 + q;
  const bf16* vb = V + h * 32 + dg * 4;
  float a0 = 0.f, a1 = 0.f, a2 = 0.f, a3 = 0.f;
#pragma unroll
  for (int i = 0; i < 16; ++i) {
    const int4 idx = sIdx[(q * 16 + i) * 8 + h];
    const float4 w = sW[(q * 16 + i) * 8 + h];
    {
      const uint2 u = *(const uint2*)(vb + (size_t)idx.x * 256);
      a0 = fmaf(w.x, bflo(u.x), a0); a1 = fmaf(w.x, bfhi(u.x), a1);
      a2 = fmaf(w.x, bflo(u.y), a2); a3 = fmaf(w.x, bfhi(u.y), a3);
    }
    {
      const uint2 u = *(const uint2*)(vb + (size_t)idx.y * 256);
      a0 = fmaf(w.y, bflo(u.x), a0); a1 = fmaf(w.y, bfhi(u.x), a1);
      a2 = fmaf(w.y, bflo(u.y), a2); a3 = fmaf(w.y, bfhi(u.y), a3);
    }
    {
      const uint2 u = *(const uint2*)(vb + (size_t)idx.z * 256);
      a0 = fmaf(w.z, bflo(u.x), a0); a1 = fmaf(w.z, bfhi(u.x), a1);
      a2 = fmaf(w.z, bflo(u.y), a2); a3 = fmaf(w.z, bfhi(u.y), a3);
    }
    {
      const uint2 u = *(const uint2*)(vb + (size_t)idx.w * 256);
      a0 = fmaf(w.w, bflo(u.x), a0); a1 = fmaf(w.w, bfhi(u.x), a1);
      a2 = fmaf(w.w, bflo(u.y), a2); a3 = fmaf(w.w, bfhi(u.y), a3);
    }
  }
  float4 o; o.x = a0; o.y = a1; o.z = a2; o.w = a3;
  *(float4*)(outb + (size_t)row * 256 + h * 32 + dg * 4) = o;
}

// ---------------- K4: update = outb @ Wout + bout; LN(qf + update) ----------
__global__ __launch_bounds__(256) void k_outln(const float* __restrict__ outb,
                                               const float* __restrict__ W,
                                               const float* __restrict__ bias,
                                               const float* __restrict__ qf,
                                               const float* __restrict__ gamma,
                                               const float* __restrict__ beta,
                                               float* __restrict__ y) {
  __shared__ float As[TM * EMB];  // A tile, reused as x tile for LN
  const int tid = threadIdx.x;
  const int row0 = blockIdx.x * TM;
  const float4* Ag = (const float4*)(outb + (size_t)row0 * EMB);
  float4* As4 = (float4*)As;
#pragma unroll
  for (int j = 0; j < 8; ++j) As4[tid + j * 256] = Ag[tid + j * 256];
  __syncthreads();
  const int tcol = tid & 63, trow = tid >> 6;
  float acc[8][4];
#pragma unroll
  for (int r = 0; r < 8; ++r)
#pragma unroll
    for (int s = 0; s < 4; ++s) acc[r][s] = 0.f;
  for (int k4 = 0; k4 < 64; ++k4) {
    float4 a[8];
#pragma unroll
    for (int r = 0; r < 8; ++r) a[r] = As4[(trow * 8 + r) * 64 + k4];
#pragma unroll
    for (int i = 0; i < 4; ++i) {
      const int k = k4 * 4 + i;
      float wv[4];
#pragma unroll
      for (int s = 0; s < 4; ++s) wv[s] = W[k * EMB + tcol + 64 * s];
#pragma unroll
      for (int r = 0; r < 8; ++r) {
        const float av = (i == 0) ? a[r].x : (i == 1) ? a[r].y : (i == 2) ? a[r].z : a[r].w;
#pragma unroll
        for (int s = 0; s < 4; ++s) acc[r][s] = fmaf(av, wv[s], acc[r][s]);
      }
    }
  }
  __syncthreads();  // everyone done reading A tile; reuse As as x tile
#pragma unroll
  for (int r = 0; r < 8; ++r) {
    const int row = row0 + trow * 8 + r;
#pragma unroll
    for (int s = 0; s < 4; ++s) {
      const int c = tcol + 64 * s;
      As[(trow * 8 + r) * 256 + c] = acc[r][s] + bias[c] + qf[(size_t)row * 256 + c];
    }
  }
  __syncthreads();
  const int lane = tid & 63, wv = tid >> 6;
#pragma unroll
  for (int rr = 0; rr < 8; ++rr) {
    const int r = wv * 8 + rr;
    float s1 = 0.f, s2 = 0.f;
#pragma unroll
    for (int i = 0; i < 4; ++i) {
      const float xv = As[r * 256 + lane + 64 * i];
      s1 += xv; s2 += xv * xv;
    }
#pragma unroll
    for (int o = 32; o >= 1; o >>= 1) {
      s1 += __shfl_xor(s1, o);
      s2 += __shfl_xor(s2, o);
    }
    const float mu = s1 * (1.f / 256.f);
    const float var = s2 * (1.f / 256.f) - mu * mu;
    const float rsig = rsqrtf(var + LN_EPS);
#pragma unroll
    for (int i = 0; i < 4; ++i) {
      const int c = lane + 64 * i;
      const float xv = As[r * 256 + c];
      y[(size_t)(row0 + r) * 256 + c] = (xv - mu) * rsig * gamma[c] + beta[c];
    }
  }
}

extern "C" void kernel_launch(void* const* d_in, const int* in_sizes, int n_in,
                              void* d_out, int out_size, void* d_ws, size_t ws_size,
                              hipStream_t stream) {
  const float* img_feat = (const float*)d_in[0];
  // d_in[1] = img_shapes (hardcoded: (128,128),(64,64),(32,32),(16,16))
  const unsigned char* img_mask = (const unsigned char*)d_in[2];
  const float* vratio = (const float*)d_in[3];
  const float* qf = (const float*)d_in[4];
  const float* qp = (const float*)d_in[5];
  const float* qpts = (const float*)d_in[6];
  const float* Wv = (const float*)d_in[7];
  const float* bv = (const float*)d_in[8];
  const float* Woff = (const float*)d_in[9];
  const float* boff = (const float*)d_in[10];
  const float* Wattn = (const float*)d_in[11];
  const float* battn = (const float*)d_in[12];
  const float* Wout = (const float*)d_in[13];
  const float* bout = (const float*)d_in[14];
  const float* gamma = (const float*)d_in[15];
  const float* beta = (const float*)d_in[16];

  char* ws = (char*)d_ws;
  bf16* V = (bf16*)ws;                                       // NROW*256 bf16
  bf16* off = (bf16*)(ws + (size_t)NROW * 256 * 2);          // NROW*256 bf16
  bf16* lg = (bf16*)(ws + (size_t)NROW * 256 * 4);           // NROW*128 bf16
  float* outb = (float*)d_out;  // reuse d_out as sampled-out scratch

  dim3 blk(256);
  k_value<<<NROW / TM, blk, 0, stream>>>(img_feat, Wv, bv, img_mask, V);
  k_offattn<<<NROW / TM, blk, 0, stream>>>(qf, qp, Woff, boff, Wattn, battn, off, lg);
  k_sample<<<NROW / QB, blk, 0, stream>>>(V, off, lg, qpts, vratio, outb);
  k_outln<<<NROW / TM, blk, 0, stream>>>(outb, Wout, bout, qf, gamma, beta, (float*)d_out);
}

// Round 8
// 312.926 us; speedup vs baseline: 1.8516x; 1.3242x over previous
//
#include <hip/hip_runtime.h>
#include <hip/hip_bf16.h>

#define EMB 256
#define SEQ 21760
#define NB 2
#define NROW (NB * SEQ)   // 43520
#define TM 32
#define QB 4
#define LN_EPS 1e-5f

typedef __hip_bfloat16 bf16;
typedef short bf16x8 __attribute__((ext_vector_type(8)));
typedef float f32x4 __attribute__((ext_vector_type(4)));

__device__ __forceinline__ unsigned short f2bf(float f) {
  __hip_bfloat16 h = __float2bfloat16(f);
  return *reinterpret_cast<unsigned short*>(&h);
}
__device__ __forceinline__ float bf2f(unsigned short u) {
  return __uint_as_float((unsigned int)u << 16);
}
__device__ __forceinline__ float bflo(unsigned int u) { return __uint_as_float(u << 16); }
__device__ __forceinline__ float bfhi(unsigned int u) { return __uint_as_float(u & 0xffff0000u); }

// split f into hi/lo bf16 pair: hi = bf16(f), lo = bf16(f - hi)
__device__ __forceinline__ void split2(float f, unsigned short& hi, unsigned short& lo) {
  hi = f2bf(f);
  lo = f2bf(f - bf2f(hi));
}

// 3-term compensated MFMA: (ah+al)*(bh+bl) minus the ~2^-18 al*bl term
#define MFMA3(ACC, AH, AL, BH, BL)                                              \
  ACC = __builtin_amdgcn_mfma_f32_16x16x32_bf16(AL, BH, ACC, 0, 0, 0);          \
  ACC = __builtin_amdgcn_mfma_f32_16x16x32_bf16(AH, BL, ACC, 0, 0, 0);          \
  ACC = __builtin_amdgcn_mfma_f32_16x16x32_bf16(AH, BH, ACC, 0, 0, 0);

// ---------------- K0: hi/lo bf16 transpose of W[k][n] -> Wt[n][k] -----------
__global__ __launch_bounds__(256) void k_trans(const float* __restrict__ src,
                                               unsigned short* __restrict__ dh,
                                               unsigned short* __restrict__ dl, int N) {
  const int n = blockIdx.x, k = threadIdx.x;
  unsigned short hi, lo;
  split2(src[k * N + n], hi, lo);
  dh[n * 256 + k] = hi;
  dl[n * 256 + k] = lo;
}

// ---------------- K1: V = mask ? 0 : (img_feat @ Wv + bv)  -> bf16 ----------
// BM=64, 4 waves, wave w owns cols [w*64, w*64+64). K=256 (8 steps of 32).
__global__ __launch_bounds__(256) void k_value(const float* __restrict__ A,
                                               const unsigned short* __restrict__ WtH,
                                               const unsigned short* __restrict__ WtL,
                                               const float* __restrict__ bias,
                                               const unsigned char* __restrict__ mask,
                                               bf16* __restrict__ V) {
  __shared__ unsigned short AsH[64 * 256];  // 32KB each, XOR-swizzled
  __shared__ unsigned short AsL[64 * 256];
  const int tid = threadIdx.x;
  const int lane = tid & 63, w = tid >> 6;
  const int row0 = blockIdx.x * 64;
#pragma unroll
  for (int it = 0; it < 8; ++it) {
    const int cid = it * 256 + tid;
    const int row = cid >> 5, c = cid & 31;
    const float4* p = (const float4*)(A + (size_t)(row0 + row) * 256 + c * 8);
    const float4 a0 = p[0], a1 = p[1];
    union { unsigned short u[8]; uint4 q; } ph, pl;
    split2(a0.x, ph.u[0], pl.u[0]); split2(a0.y, ph.u[1], pl.u[1]);
    split2(a0.z, ph.u[2], pl.u[2]); split2(a0.w, ph.u[3], pl.u[3]);
    split2(a1.x, ph.u[4], pl.u[4]); split2(a1.y, ph.u[5], pl.u[5]);
    split2(a1.z, ph.u[6], pl.u[6]); split2(a1.w, ph.u[7], pl.u[7]);
    const int boff_ = row * 512 + ((c * 16) ^ ((row & 7) << 4));
    *(uint4*)((char*)AsH + boff_) = ph.q;
    *(uint4*)((char*)AsL + boff_) = pl.q;
  }
  __syncthreads();
  const int lg16 = lane >> 4, l16 = lane & 15;
  f32x4 acc[4][4] = {};
#pragma unroll
  for (int kk = 0; kk < 8; ++kk) {
    bf16x8 afh[4], afl[4], bh[4], bl[4];
#pragma unroll
    for (int mf = 0; mf < 4; ++mf) {
      const int row = mf * 16 + l16;
      const int boff_ = row * 512 + ((kk * 64 + lg16 * 16) ^ ((row & 7) << 4));
      afh[mf] = *(const bf16x8*)((const char*)AsH + boff_);
      afl[mf] = *(const bf16x8*)((const char*)AsL + boff_);
    }
#pragma unroll
    for (int nf = 0; nf < 4; ++nf) {
      const int col = w * 64 + nf * 16 + l16;
      bh[nf] = *(const bf16x8*)(WtH + (size_t)col * 256 + kk * 32 + lg16 * 8);
      bl[nf] = *(const bf16x8*)(WtL + (size_t)col * 256 + kk * 32 + lg16 * 8);
    }
#pragma unroll
    for (int mf = 0; mf < 4; ++mf)
#pragma unroll
      for (int nf = 0; nf < 4; ++nf) {
        MFMA3(acc[mf][nf], afh[mf], afl[mf], bh[nf], bl[nf]);
      }
  }
#pragma unroll
  for (int mf = 0; mf < 4; ++mf) {
    const int rbase = mf * 16 + lg16 * 4;
    const uchar4 mk = *(const uchar4*)(mask + row0 + rbase);
#pragma unroll
    for (int nf = 0; nf < 4; ++nf) {
      const int col = w * 64 + nf * 16 + l16;
      const float bb = bias[col];
#pragma unroll
      for (int r = 0; r < 4; ++r) {
        const unsigned char m = (r == 0) ? mk.x : (r == 1) ? mk.y : (r == 2) ? mk.z : mk.w;
        const float v = m ? 0.f : (acc[mf][nf][r] + bb);
        V[(size_t)(row0 + rbase + r) * 256 + col] = __float2bfloat16(v);
      }
    }
  }
}

// ---------------- K2: q = qf+qp; [off|lg] = q @ Wcat -> bf16 ----------------
// BM=64, 4 waves, wave w owns cols [w*96, w*96+96) of N=384.
__global__ __launch_bounds__(256) void k_offattn(const float* __restrict__ qf,
                                                 const float* __restrict__ qp,
                                                 const unsigned short* __restrict__ WtH,
                                                 const unsigned short* __restrict__ WtL,
                                                 const float* __restrict__ boff,
                                                 const float* __restrict__ battn,
                                                 bf16* __restrict__ off,
                                                 bf16* __restrict__ lg) {
  __shared__ unsigned short AsH[64 * 256];
  __shared__ unsigned short AsL[64 * 256];
  const int tid = threadIdx.x;
  const int lane = tid & 63, w = tid >> 6;
  const int row0 = blockIdx.x * 64;
#pragma unroll
  for (int it = 0; it < 8; ++it) {
    const int cid = it * 256 + tid;
    const int row = cid >> 5, c = cid & 31;
    const float4* pf = (const float4*)(qf + (size_t)(row0 + row) * 256 + c * 8);
    const float4* pp = (const float4*)(qp + (size_t)(row0 + row) * 256 + c * 8);
    const float4 a0 = pf[0], a1 = pf[1], b0 = pp[0], b1 = pp[1];
    union { unsigned short u[8]; uint4 q; } ph, pl;
    split2(a0.x + b0.x, ph.u[0], pl.u[0]); split2(a0.y + b0.y, ph.u[1], pl.u[1]);
    split2(a0.z + b0.z, ph.u[2], pl.u[2]); split2(a0.w + b0.w, ph.u[3], pl.u[3]);
    split2(a1.x + b1.x, ph.u[4], pl.u[4]); split2(a1.y + b1.y, ph.u[5], pl.u[5]);
    split2(a1.z + b1.z, ph.u[6], pl.u[6]); split2(a1.w + b1.w, ph.u[7], pl.u[7]);
    const int boff_ = row * 512 + ((c * 16) ^ ((row & 7) << 4));
    *(uint4*)((char*)AsH + boff_) = ph.q;
    *(uint4*)((char*)AsL + boff_) = pl.q;
  }
  __syncthreads();
  const int lg16 = lane >> 4, l16 = lane & 15;
  f32x4 acc[4][6] = {};
#pragma unroll
  for (int kk = 0; kk < 8; ++kk) {
    bf16x8 afh[4], afl[4], bh[6], bl[6];
#pragma unroll
    for (int mf = 0; mf < 4; ++mf) {
      const int row = mf * 16 + l16;
      const int boff_ = row * 512 + ((kk * 64 + lg16 * 16) ^ ((row & 7) << 4));
      afh[mf] = *(const bf16x8*)((const char*)AsH + boff_);
      afl[mf] = *(const bf16x8*)((const char*)AsL + boff_);
    }
#pragma unroll
    for (int nf = 0; nf < 6; ++nf) {
      const int col = w * 96 + nf * 16 + l16;
      bh[nf] = *(const bf16x8*)(WtH + (size_t)col * 256 + kk * 32 + lg16 * 8);
      bl[nf] = *(const bf16x8*)(WtL + (size_t)col * 256 + kk * 32 + lg16 * 8);
    }
#pragma unroll
    for (int mf = 0; mf < 4; ++mf)
#pragma unroll
      for (int nf = 0; nf < 6; ++nf) {
        MFMA3(acc[mf][nf], afh[mf], afl[mf], bh[nf], bl[nf]);
      }
  }
#pragma unroll
  for (int mf = 0; mf < 4; ++mf) {
    const int rbase = row0 + mf * 16 + lg16 * 4;
#pragma unroll
    for (int nf = 0; nf < 6; ++nf) {
      const int col = w * 96 + nf * 16 + l16;
      if (col < 256) {
        const float bb = boff[col];
#pragma unroll
        for (int r = 0; r < 4; ++r)
          off[(size_t)(rbase + r) * 256 + col] = __float2bfloat16(acc[mf][nf][r] + bb);
      } else {
        const float bb = battn[col - 256];
#pragma unroll
        for (int r = 0; r < 4; ++r)
          lg[(size_t)(rbase + r) * 128 + (col - 256)] = __float2bfloat16(acc[mf][nf][r] + bb);
      }
    }
  }
}

// ---------------- K3: softmax + bilinear gather + attn-weighted sum ---------
// (byte-identical to round 7)
__global__ __launch_bounds__(256) void k_sample(const bf16* __restrict__ V,
                                                const bf16* __restrict__ off,
                                                const bf16* __restrict__ lg,
                                                const float* __restrict__ qpts,
                                                const float* __restrict__ vratio,
                                                float* __restrict__ outb) {
  __shared__ int4 sIdx[QB * 16 * 8];   // [q][i][h]
  __shared__ float4 sW[QB * 16 * 8];
  __shared__ float sMax[QB * 8], sInv[QB * 8];
  const int t = threadIdx.x;
  const int row0 = blockIdx.x * QB;

  if (t < QB * 8) {
    const int q = t >> 3, h = t & 7;
    const int row = row0 + q;
    const uint4* lp = (const uint4*)(lg + (size_t)row * 128 + h * 16);
    uint4 u0 = lp[0], u1 = lp[1];
    float v[16];
    v[0] = bflo(u0.x); v[1] = bfhi(u0.x); v[2] = bflo(u0.y); v[3] = bfhi(u0.y);
    v[4] = bflo(u0.z); v[5] = bfhi(u0.z); v[6] = bflo(u0.w); v[7] = bfhi(u0.w);
    v[8] = bflo(u1.x); v[9] = bfhi(u1.x); v[10] = bflo(u1.y); v[11] = bfhi(u1.y);
    v[12] = bflo(u1.z); v[13] = bfhi(u1.z); v[14] = bflo(u1.w); v[15] = bfhi(u1.w);
    float m = v[0];
#pragma unroll
    for (int i = 1; i < 16; ++i) m = fmaxf(m, v[i]);
    float s = 0.f;
#pragma unroll
    for (int i = 0; i < 16; ++i) s += __expf(v[i] - m);
    sMax[t] = m;
    sInv[t] = 1.f / s;
  }
  __syncthreads();

  const int Wl_[4] = {128, 64, 32, 16};
  const int st_[4] = {0, 16384, 20480, 21504};
#pragma unroll
  for (int tt = 0; tt < 2; ++tt) {
    const int sid = t + tt * 256;
    const int q = sid >> 7, s = sid & 127;
    const int h = s >> 4, i = s & 15, l = i >> 2;
    const int row = row0 + q;
    const int b = row >= SEQ;  // NB == 2
    const unsigned int u = *(const unsigned int*)(off + (size_t)row * 256 + s * 2);
    const float ox = bflo(u), oy = bfhi(u);
    const float lgv = bf2f(*(const unsigned short*)(lg + (size_t)row * 128 + s));
    const float e = __expf(lgv - sMax[q * 8 + h]) * sInv[q * 8 + h];
    const float px = qpts[(size_t)row * 2], py = qpts[(size_t)row * 2 + 1];
    const float vrx = vratio[b * 8 + l * 2], vry = vratio[b * 8 + l * 2 + 1];
    const int Wl = Wl_[l];
    const float fW = (float)Wl;
    const float x = fmaf(px * vrx, fW, ox) - 0.5f;
    const float y = fmaf(py * vry, fW, oy) - 0.5f;
    const float fx = floorf(x), fy = floorf(y);
    const float wx = x - fx, wy = y - fy;
    const int x0 = (int)fx, y0 = (int)fy;
    const int x1 = x0 + 1, y1 = y0 + 1;
    const int xc0 = min(max(x0, 0), Wl - 1), xc1 = min(max(x1, 0), Wl - 1);
    const int yc0 = min(max(y0, 0), Wl - 1), yc1 = min(max(y1, 0), Wl - 1);
    const float ox0 = (x0 >= 0 && x0 < Wl) ? e : 0.f;
    const float ox1 = (x1 >= 0 && x1 < Wl) ? e : 0.f;
    const float oy0 = (y0 >= 0 && y0 < Wl) ? 1.f : 0.f;
    const float oy1 = (y1 >= 0 && y1 < Wl) ? 1.f : 0.f;
    const int base = b * SEQ + st_[l];
    const int r0 = base + yc0 * Wl, r1 = base + yc1 * Wl;
    sIdx[(q * 16 + i) * 8 + h] = make_int4(r0 + xc0, r0 + xc1, r1 + xc0, r1 + xc1);
    sW[(q * 16 + i) * 8 + h] =
        make_float4((1.f - wx) * (1.f - wy) * ox0 * oy0, wx * (1.f - wy) * ox1 * oy0,
                    (1.f - wx) * wy * ox0 * oy1, wx * wy * ox1 * oy1);
  }
  __syncthreads();

  const int q = t >> 6, sub = t & 63;
  const int h = sub >> 3, dg = sub & 7;
  const int row = row0 + q;
  const bf16* vb = V + h * 32 + dg * 4;
  float a0 = 0.f, a1 = 0.f, a2 = 0.f, a3 = 0.f;
#pragma unroll
  for (int i = 0; i < 16; ++i) {
    const int4 idx = sIdx[(q * 16 + i) * 8 + h];
    const float4 w = sW[(q * 16 + i) * 8 + h];
    {
      const uint2 u = *(const uint2*)(vb + (size_t)idx.x * 256);
      a0 = fmaf(w.x, bflo(u.x), a0); a1 = fmaf(w.x, bfhi(u.x), a1);
      a2 = fmaf(w.x, bflo(u.y), a2); a3 = fmaf(w.x, bfhi(u.y), a3);
    }
    {
      const uint2 u = *(const uint2*)(vb + (size_t)idx.y * 256);
      a0 = fmaf(w.y, bflo(u.x), a0); a1 = fmaf(w.y, bfhi(u.x), a1);
      a2 = fmaf(w.y, bflo(u.y), a2); a3 = fmaf(w.y, bfhi(u.y), a3);
    }
    {
      const uint2 u = *(const uint2*)(vb + (size_t)idx.z * 256);
      a0 = fmaf(w.z, bflo(u.x), a0); a1 = fmaf(w.z, bfhi(u.x), a1);
      a2 = fmaf(w.z, bflo(u.y), a2); a3 = fmaf(w.z, bfhi(u.y), a3);
    }
    {
      const uint2 u = *(const uint2*)(vb + (size_t)idx.w * 256);
      a0 = fmaf(w.w, bflo(u.x), a0); a1 = fmaf(w.w, bfhi(u.x), a1);
      a2 = fmaf(w.w, bflo(u.y), a2); a3 = fmaf(w.w, bfhi(u.y), a3);
    }
  }
  float4 o; o.x = a0; o.y = a1; o.z = a2; o.w = a3;
  *(float4*)(outb + (size_t)row * 256 + h * 32 + dg * 4) = o;
}

// ---------------- K4: update = outb @ Wout + bout; LN(qf + update) ----------
// (byte-identical to round 7: fp32 vector-ALU GEMM)
__global__ __launch_bounds__(256) void k_outln(const float* __restrict__ outb,
                                               const float* __restrict__ W,
                                               const float* __restrict__ bias,
                                               const float* __restrict__ qf,
                                               const float* __restrict__ gamma,
                                               const float* __restrict__ beta,
                                               float* __restrict__ y) {
  __shared__ float As[TM * EMB];  // A tile, reused as x tile for LN
  const int tid = threadIdx.x;
  const int row0 = blockIdx.x * TM;
  const float4* Ag = (const float4*)(outb + (size_t)row0 * EMB);
  float4* As4 = (float4*)As;
#pragma unroll
  for (int j = 0; j < 8; ++j) As4[tid + j * 256] = Ag[tid + j * 256];
  __syncthreads();
  const int tcol = tid & 63, trow = tid >> 6;
  float acc[8][4];
#pragma unroll
  for (int r = 0; r < 8; ++r)
#pragma unroll
    for (int s = 0; s < 4; ++s) acc[r][s] = 0.f;
  for (int k4 = 0; k4 < 64; ++k4) {
    float4 a[8];
#pragma unroll
    for (int r = 0; r < 8; ++r) a[r] = As4[(trow * 8 + r) * 64 + k4];
#pragma unroll
    for (int i = 0; i < 4; ++i) {
      const int k = k4 * 4 + i;
      float wv[4];
#pragma unroll
      for (int s = 0; s < 4; ++s) wv[s] = W[k * EMB + tcol + 64 * s];
#pragma unroll
      for (int r = 0; r < 8; ++r) {
        const float av = (i == 0) ? a[r].x : (i == 1) ? a[r].y : (i == 2) ? a[r].z : a[r].w;
#pragma unroll
        for (int s = 0; s < 4; ++s) acc[r][s] = fmaf(av, wv[s], acc[r][s]);
      }
    }
  }
  __syncthreads();
#pragma unroll
  for (int r = 0; r < 8; ++r) {
    const int row = row0 + trow * 8 + r;
#pragma unroll
    for (int s = 0; s < 4; ++s) {
      const int c = tcol + 64 * s;
      As[(trow * 8 + r) * 256 + c] = acc[r][s] + bias[c] + qf[(size_t)row * 256 + c];
    }
  }
  __syncthreads();
  const int lane = tid & 63, wv = tid >> 6;
#pragma unroll
  for (int rr = 0; rr < 8; ++rr) {
    const int r = wv * 8 + rr;
    float s1 = 0.f, s2 = 0.f;
#pragma unroll
    for (int i = 0; i < 4; ++i) {
      const float xv = As[r * 256 + lane + 64 * i];
      s1 += xv; s2 += xv * xv;
    }
#pragma unroll
    for (int o = 32; o >= 1; o >>= 1) {
      s1 += __shfl_xor(s1, o);
      s2 += __shfl_xor(s2, o);
    }
    const float mu = s1 * (1.f / 256.f);
    const float var = s2 * (1.f / 256.f) - mu * mu;
    const float rsig = rsqrtf(var + LN_EPS);
#pragma unroll
    for (int i = 0; i < 4; ++i) {
      const int c = lane + 64 * i;
      const float xv = As[r * 256 + c];
      y[(size_t)(row0 + r) * 256 + c] = (xv - mu) * rsig * gamma[c] + beta[c];
    }
  }
}

extern "C" void kernel_launch(void* const* d_in, const int* in_sizes, int n_in,
                              void* d_out, int out_size, void* d_ws, size_t ws_size,
                              hipStream_t stream) {
  const float* img_feat = (const float*)d_in[0];
  const unsigned char* img_mask = (const unsigned char*)d_in[2];
  const float* vratio = (const float*)d_in[3];
  const float* qf = (const float*)d_in[4];
  const float* qp = (const float*)d_in[5];
  const float* qpts = (const float*)d_in[6];
  const float* Wv = (const float*)d_in[7];
  const float* bv = (const float*)d_in[8];
  const float* Woff = (const float*)d_in[9];
  const float* boff = (const float*)d_in[10];
  const float* Wattn = (const float*)d_in[11];
  const float* battn = (const float*)d_in[12];
  const float* Wout = (const float*)d_in[13];
  const float* bout = (const float*)d_in[14];
  const float* gamma = (const float*)d_in[15];
  const float* beta = (const float*)d_in[16];

  char* ws = (char*)d_ws;
  bf16* V = (bf16*)ws;                                       // 22.3 MB
  bf16* off = (bf16*)(ws + (size_t)NROW * 256 * 2);          // 22.3 MB
  bf16* lg = (bf16*)(ws + (size_t)NROW * 256 * 4);           // 11.1 MB
  unsigned short* wbase =
      (unsigned short*)(ws + (size_t)NROW * 256 * 4 + (size_t)NROW * 128 * 2);
  unsigned short* WvH = wbase;                 // 65536
  unsigned short* WvL = WvH + 65536;           // 65536
  unsigned short* WcatH = WvL + 65536;         // 98304
  unsigned short* WcatL = WcatH + 98304;       // 98304
  float* outb = (float*)d_out;  // fp32 sampled-out scratch (reused as y)

  dim3 blk(256);
  k_trans<<<256, blk, 0, stream>>>(Wv, WvH, WvL, 256);
  k_trans<<<256, blk, 0, stream>>>(Woff, WcatH, WcatL, 256);
  k_trans<<<128, blk, 0, stream>>>(Wattn, WcatH + 256 * 256, WcatL + 256 * 256, 128);
  k_value<<<NROW / 64, blk, 0, stream>>>(img_feat, WvH, WvL, bv, img_mask, V);
  k_offattn<<<NROW / 64, blk, 0, stream>>>(qf, qp, WcatH, WcatL, boff, battn, off, lg);
  k_sample<<<NROW / QB, blk, 0, stream>>>(V, off, lg, qpts, vratio, outb);
  k_outln<<<NROW / TM, blk, 0, stream>>>(outb, Wout, bout, qf, gamma, beta, (float*)d_out);
}

// Round 10
// 312.769 us; speedup vs baseline: 1.8525x; 1.0005x over previous
//
#include <hip/hip_runtime.h>
#include <hip/hip_bf16.h>

#define EMB 256
#define SEQ 21760
#define NB 2
#define NROW (NB * SEQ)   // 43520
#define TM 32
#define QB 8              // queries per k_sample block
#define LN_EPS 1e-5f

typedef __hip_bfloat16 bf16;
typedef short bf16x8 __attribute__((ext_vector_type(8)));
typedef float f32x4 __attribute__((ext_vector_type(4)));

__device__ __forceinline__ unsigned short f2bf(float f) {
  __hip_bfloat16 h = __float2bfloat16(f);
  return *reinterpret_cast<unsigned short*>(&h);
}
__device__ __forceinline__ float bf2f(unsigned short u) {
  return __uint_as_float((unsigned int)u << 16);
}
__device__ __forceinline__ float bflo(unsigned int u) { return __uint_as_float(u << 16); }
__device__ __forceinline__ float bfhi(unsigned int u) { return __uint_as_float(u & 0xffff0000u); }

// split f into hi/lo bf16 pair: hi = bf16(f), lo = bf16(f - hi)
__device__ __forceinline__ void split2(float f, unsigned short& hi, unsigned short& lo) {
  hi = f2bf(f);
  lo = f2bf(f - bf2f(hi));
}

// 3-term compensated MFMA (proven exact-enough in k_value/k_offattn, round 8)
#define MFMA3(ACC, AH, AL, BH, BL)                                              \
  ACC = __builtin_amdgcn_mfma_f32_16x16x32_bf16(AL, BH, ACC, 0, 0, 0);          \
  ACC = __builtin_amdgcn_mfma_f32_16x16x32_bf16(AH, BL, ACC, 0, 0, 0);          \
  ACC = __builtin_amdgcn_mfma_f32_16x16x32_bf16(AH, BH, ACC, 0, 0, 0);

// ---------------- K0: hi/lo bf16 transpose of W[k][n] -> Wt[n][k] -----------
__global__ __launch_bounds__(256) void k_trans(const float* __restrict__ src,
                                               unsigned short* __restrict__ dh,
                                               unsigned short* __restrict__ dl, int N) {
  const int n = blockIdx.x, k = threadIdx.x;
  unsigned short hi, lo;
  split2(src[k * N + n], hi, lo);
  dh[n * 256 + k] = hi;
  dl[n * 256 + k] = lo;
}

// ---------------- K1: V = mask ? 0 : (img_feat @ Wv + bv)  -> bf16 ----------
// (byte-identical to round 8 — proven)
__global__ __launch_bounds__(256) void k_value(const float* __restrict__ A,
                                               const unsigned short* __restrict__ WtH,
                                               const unsigned short* __restrict__ WtL,
                                               const float* __restrict__ bias,
                                               const unsigned char* __restrict__ mask,
                                               bf16* __restrict__ V) {
  __shared__ unsigned short AsH[64 * 256];  // 32KB each, XOR-swizzled
  __shared__ unsigned short AsL[64 * 256];
  const int tid = threadIdx.x;
  const int lane = tid & 63, w = tid >> 6;
  const int row0 = blockIdx.x * 64;
#pragma unroll
  for (int it = 0; it < 8; ++it) {
    const int cid = it * 256 + tid;
    const int row = cid >> 5, c = cid & 31;
    const float4* p = (const float4*)(A + (size_t)(row0 + row) * 256 + c * 8);
    const float4 a0 = p[0], a1 = p[1];
    union { unsigned short u[8]; uint4 q; } ph, pl;
    split2(a0.x, ph.u[0], pl.u[0]); split2(a0.y, ph.u[1], pl.u[1]);
    split2(a0.z, ph.u[2], pl.u[2]); split2(a0.w, ph.u[3], pl.u[3]);
    split2(a1.x, ph.u[4], pl.u[4]); split2(a1.y, ph.u[5], pl.u[5]);
    split2(a1.z, ph.u[6], pl.u[6]); split2(a1.w, ph.u[7], pl.u[7]);
    const int boff_ = row * 512 + ((c * 16) ^ ((row & 7) << 4));
    *(uint4*)((char*)AsH + boff_) = ph.q;
    *(uint4*)((char*)AsL + boff_) = pl.q;
  }
  __syncthreads();
  const int lg16 = lane >> 4, l16 = lane & 15;
  f32x4 acc[4][4] = {};
#pragma unroll
  for (int kk = 0; kk < 8; ++kk) {
    bf16x8 afh[4], afl[4], bh[4], bl[4];
#pragma unroll
    for (int mf = 0; mf < 4; ++mf) {
      const int row = mf * 16 + l16;
      const int boff_ = row * 512 + ((kk * 64 + lg16 * 16) ^ ((row & 7) << 4));
      afh[mf] = *(const bf16x8*)((const char*)AsH + boff_);
      afl[mf] = *(const bf16x8*)((const char*)AsL + boff_);
    }
#pragma unroll
    for (int nf = 0; nf < 4; ++nf) {
      const int col = w * 64 + nf * 16 + l16;
      bh[nf] = *(const bf16x8*)(WtH + (size_t)col * 256 + kk * 32 + lg16 * 8);
      bl[nf] = *(const bf16x8*)(WtL + (size_t)col * 256 + kk * 32 + lg16 * 8);
    }
#pragma unroll
    for (int mf = 0; mf < 4; ++mf)
#pragma unroll
      for (int nf = 0; nf < 4; ++nf) {
        MFMA3(acc[mf][nf], afh[mf], afl[mf], bh[nf], bl[nf]);
      }
  }
#pragma unroll
  for (int mf = 0; mf < 4; ++mf) {
    const int rbase = mf * 16 + lg16 * 4;
    const uchar4 mk = *(const uchar4*)(mask + row0 + rbase);
#pragma unroll
    for (int nf = 0; nf < 4; ++nf) {
      const int col = w * 64 + nf * 16 + l16;
      const float bb = bias[col];
#pragma unroll
      for (int r = 0; r < 4; ++r) {
        const unsigned char m = (r == 0) ? mk.x : (r == 1) ? mk.y : (r == 2) ? mk.z : mk.w;
        const float v = m ? 0.f : (acc[mf][nf][r] + bb);
        V[(size_t)(row0 + rbase + r) * 256 + col] = __float2bfloat16(v);
      }
    }
  }
}

// ---------------- K2: q = qf+qp; [off|lg] = q @ Wcat -> bf16 ----------------
// (byte-identical to round 8 — proven)
__global__ __launch_bounds__(256) void k_offattn(const float* __restrict__ qf,
                                                 const float* __restrict__ qp,
                                                 const unsigned short* __restrict__ WtH,
                                                 const unsigned short* __restrict__ WtL,
                                                 const float* __restrict__ boff,
                                                 const float* __restrict__ battn,
                                                 bf16* __restrict__ off,
                                                 bf16* __restrict__ lg) {
  __shared__ unsigned short AsH[64 * 256];
  __shared__ unsigned short AsL[64 * 256];
  const int tid = threadIdx.x;
  const int lane = tid & 63, w = tid >> 6;
  const int row0 = blockIdx.x * 64;
#pragma unroll
  for (int it = 0; it < 8; ++it) {
    const int cid = it * 256 + tid;
    const int row = cid >> 5, c = cid & 31;
    const float4* pf = (const float4*)(qf + (size_t)(row0 + row) * 256 + c * 8);
    const float4* pp = (const float4*)(qp + (size_t)(row0 + row) * 256 + c * 8);
    const float4 a0 = pf[0], a1 = pf[1], b0 = pp[0], b1 = pp[1];
    union { unsigned short u[8]; uint4 q; } ph, pl;
    split2(a0.x + b0.x, ph.u[0], pl.u[0]); split2(a0.y + b0.y, ph.u[1], pl.u[1]);
    split2(a0.z + b0.z, ph.u[2], pl.u[2]); split2(a0.w + b0.w, ph.u[3], pl.u[3]);
    split2(a1.x + b1.x, ph.u[4], pl.u[4]); split2(a1.y + b1.y, ph.u[5], pl.u[5]);
    split2(a1.z + b1.z, ph.u[6], pl.u[6]); split2(a1.w + b1.w, ph.u[7], pl.u[7]);
    const int boff_ = row * 512 + ((c * 16) ^ ((row & 7) << 4));
    *(uint4*)((char*)AsH + boff_) = ph.q;
    *(uint4*)((char*)AsL + boff_) = pl.q;
  }
  __syncthreads();
  const int lg16 = lane >> 4, l16 = lane & 15;
  f32x4 acc[4][6] = {};
#pragma unroll
  for (int kk = 0; kk < 8; ++kk) {
    bf16x8 afh[4], afl[4], bh[6], bl[6];
#pragma unroll
    for (int mf = 0; mf < 4; ++mf) {
      const int row = mf * 16 + l16;
      const int boff_ = row * 512 + ((kk * 64 + lg16 * 16) ^ ((row & 7) << 4));
      afh[mf] = *(const bf16x8*)((const char*)AsH + boff_);
      afl[mf] = *(const bf16x8*)((const char*)AsL + boff_);
    }
#pragma unroll
    for (int nf = 0; nf < 6; ++nf) {
      const int col = w * 96 + nf * 16 + l16;
      bh[nf] = *(const bf16x8*)(WtH + (size_t)col * 256 + kk * 32 + lg16 * 8);
      bl[nf] = *(const bf16x8*)(WtL + (size_t)col * 256 + kk * 32 + lg16 * 8);
    }
#pragma unroll
    for (int mf = 0; mf < 4; ++mf)
#pragma unroll
      for (int nf = 0; nf < 6; ++nf) {
        MFMA3(acc[mf][nf], afh[mf], afl[mf], bh[nf], bl[nf]);
      }
  }
#pragma unroll
  for (int mf = 0; mf < 4; ++mf) {
    const int rbase = row0 + mf * 16 + lg16 * 4;
#pragma unroll
    for (int nf = 0; nf < 6; ++nf) {
      const int col = w * 96 + nf * 16 + l16;
      if (col < 256) {
        const float bb = boff[col];
#pragma unroll
        for (int r = 0; r < 4; ++r)
          off[(size_t)(rbase + r) * 256 + col] = __float2bfloat16(acc[mf][nf][r] + bb);
      } else {
        const float bb = battn[col - 256];
#pragma unroll
        for (int r = 0; r < 4; ++r)
          lg[(size_t)(rbase + r) * 128 + (col - 256)] = __float2bfloat16(acc[mf][nf][r] + bb);
      }
    }
  }
}

// ---------------- K3: softmax + bilinear gather + attn-weighted sum ---------
// QB=8 queries/block. Phase 2: thread = (q, h, 8 channels), uint4 loads.
// h-dim padded to 9 to kill the 16-way LDS write conflict (9.7M/dispatch, r8).
__global__ __launch_bounds__(256) void k_sample(const bf16* __restrict__ V,
                                                const bf16* __restrict__ off,
                                                const bf16* __restrict__ lg,
                                                const float* __restrict__ qpts,
                                                const float* __restrict__ vratio,
                                                float* __restrict__ outb) {
  __shared__ int4 sIdx[QB * 16 * 9];   // [q][i][h(pad 9)]  18.4KB
  __shared__ float4 sW[QB * 16 * 9];   // 18.4KB
  __shared__ float sMax[QB * 8], sInv[QB * 8];
  const int t = threadIdx.x;
  const int row0 = blockIdx.x * QB;

  // ---- phase 0: softmax stats per (q, head)
  if (t < QB * 8) {
    const int q = t >> 3, h = t & 7;
    const int row = row0 + q;
    const uint4* lp = (const uint4*)(lg + (size_t)row * 128 + h * 16);
    uint4 u0 = lp[0], u1 = lp[1];
    float v[16];
    v[0] = bflo(u0.x); v[1] = bfhi(u0.x); v[2] = bflo(u0.y); v[3] = bfhi(u0.y);
    v[4] = bflo(u0.z); v[5] = bfhi(u0.z); v[6] = bflo(u0.w); v[7] = bfhi(u0.w);
    v[8] = bflo(u1.x); v[9] = bfhi(u1.x); v[10] = bflo(u1.y); v[11] = bfhi(u1.y);
    v[12] = bflo(u1.z); v[13] = bfhi(u1.z); v[14] = bflo(u1.w); v[15] = bfhi(u1.w);
    float m = v[0];
#pragma unroll
    for (int i = 1; i < 16; ++i) m = fmaxf(m, v[i]);
    float s = 0.f;
#pragma unroll
    for (int i = 0; i < 16; ++i) s += __expf(v[i] - m);
    sMax[t] = m;
    sInv[t] = 1.f / s;
  }
  __syncthreads();

  // ---- phase 1: per-sample geometry, 4 tasks/thread (QB*128 = 1024 tasks)
  const int Wl_[4] = {128, 64, 32, 16};
  const int st_[4] = {0, 16384, 20480, 21504};
#pragma unroll
  for (int tt = 0; tt < 4; ++tt) {
    const int sid = t + tt * 256;
    const int q = sid >> 7, s = sid & 127;
    const int h = s >> 4, i = s & 15, l = i >> 2;
    const int row = row0 + q;
    const int b = row >= SEQ;  // NB == 2
    const unsigned int u = *(const unsigned int*)(off + (size_t)row * 256 + s * 2);
    const float ox = bflo(u), oy = bfhi(u);
    const float lgv = bf2f(*(const unsigned short*)(lg + (size_t)row * 128 + s));
    const float e = __expf(lgv - sMax[q * 8 + h]) * sInv[q * 8 + h];
    const float px = qpts[(size_t)row * 2], py = qpts[(size_t)row * 2 + 1];
    const float vrx = vratio[b * 8 + l * 2], vry = vratio[b * 8 + l * 2 + 1];
    const int Wl = Wl_[l];
    const float fW = (float)Wl;
    const float x = fmaf(px * vrx, fW, ox) - 0.5f;
    const float y = fmaf(py * vry, fW, oy) - 0.5f;
    const float fx = floorf(x), fy = floorf(y);
    const float wx = x - fx, wy = y - fy;
    const int x0 = (int)fx, y0 = (int)fy;
    const int x1 = x0 + 1, y1 = y0 + 1;
    const int xc0 = min(max(x0, 0), Wl - 1), xc1 = min(max(x1, 0), Wl - 1);
    const int yc0 = min(max(y0, 0), Wl - 1), yc1 = min(max(y1, 0), Wl - 1);
    const float ox0 = (x0 >= 0 && x0 < Wl) ? e : 0.f;   // fold attn weight in
    const float ox1 = (x1 >= 0 && x1 < Wl) ? e : 0.f;
    const float oy0 = (y0 >= 0 && y0 < Wl) ? 1.f : 0.f;
    const float oy1 = (y1 >= 0 && y1 < Wl) ? 1.f : 0.f;
    const int base = b * SEQ + st_[l];
    const int r0 = base + yc0 * Wl, r1 = base + yc1 * Wl;
    sIdx[(q * 16 + i) * 9 + h] = make_int4(r0 + xc0, r0 + xc1, r1 + xc0, r1 + xc1);
    sW[(q * 16 + i) * 9 + h] =
        make_float4((1.f - wx) * (1.f - wy) * ox0 * oy0, wx * (1.f - wy) * ox1 * oy0,
                    (1.f - wx) * wy * ox0 * oy1, wx * wy * ox1 * oy1);
  }
  __syncthreads();

  // ---- phase 2: gather + weighted accumulate; thread = (q, h, 8 channels)
  const int q = t >> 5, sub = t & 31;
  const int h = sub >> 2, dg = sub & 3;
  const int row = row0 + q;
  const bf16* vb = V + h * 32 + dg * 8;
  float a0 = 0.f, a1 = 0.f, a2 = 0.f, a3 = 0.f;
  float a4 = 0.f, a5 = 0.f, a6 = 0.f, a7 = 0.f;
#pragma unroll
  for (int i = 0; i < 16; ++i) {
    const int4 idx = sIdx[(q * 16 + i) * 9 + h];
    const float4 w = sW[(q * 16 + i) * 9 + h];
    {
      const uint4 u = *(const uint4*)(vb + (size_t)idx.x * 256);
      a0 = fmaf(w.x, bflo(u.x), a0); a1 = fmaf(w.x, bfhi(u.x), a1);
      a2 = fmaf(w.x, bflo(u.y), a2); a3 = fmaf(w.x, bfhi(u.y), a3);
      a4 = fmaf(w.x, bflo(u.z), a4); a5 = fmaf(w.x, bfhi(u.z), a5);
      a6 = fmaf(w.x, bflo(u.w), a6); a7 = fmaf(w.x, bfhi(u.w), a7);
    }
    {
      const uint4 u = *(const uint4*)(vb + (size_t)idx.y * 256);
      a0 = fmaf(w.y, bflo(u.x), a0); a1 = fmaf(w.y, bfhi(u.x), a1);
      a2 = fmaf(w.y, bflo(u.y), a2); a3 = fmaf(w.y, bfhi(u.y), a3);
      a4 = fmaf(w.y, bflo(u.z), a4); a5 = fmaf(w.y, bfhi(u.z), a5);
      a6 = fmaf(w.y, bflo(u.w), a6); a7 = fmaf(w.y, bfhi(u.w), a7);
    }
    {
      const uint4 u = *(const uint4*)(vb + (size_t)idx.z * 256);
      a0 = fmaf(w.z, bflo(u.x), a0); a1 = fmaf(w.z, bfhi(u.x), a1);
      a2 = fmaf(w.z, bflo(u.y), a2); a3 = fmaf(w.z, bfhi(u.y), a3);
      a4 = fmaf(w.z, bflo(u.z), a4); a5 = fmaf(w.z, bfhi(u.z), a5);
      a6 = fmaf(w.z, bflo(u.w), a6); a7 = fmaf(w.z, bfhi(u.w), a7);
    }
    {
      const uint4 u = *(const uint4*)(vb + (size_t)idx.w * 256);
      a0 = fmaf(w.w, bflo(u.x), a0); a1 = fmaf(w.w, bfhi(u.x), a1);
      a2 = fmaf(w.w, bflo(u.y), a2); a3 = fmaf(w.w, bfhi(u.y), a3);
      a4 = fmaf(w.w, bflo(u.z), a4); a5 = fmaf(w.w, bfhi(u.z), a5);
      a6 = fmaf(w.w, bflo(u.w), a6); a7 = fmaf(w.w, bfhi(u.w), a7);
    }
  }
  float4 o0, o1;
  o0.x = a0; o0.y = a1; o0.z = a2; o0.w = a3;
  o1.x = a4; o1.y = a5; o1.z = a6; o1.w = a7;
  float* op = outb + (size_t)row * 256 + h * 32 + dg * 8;
  *(float4*)op = o0;
  *(float4*)(op + 4) = o1;
}

// ---------------- K4: update = outb @ Wout + bout; LN(qf + update) ----------
// (byte-identical to round 8: fp32 vector-ALU GEMM — the PROVEN version;
//  the MFMA3 variant of this kernel carries an unexplained ~0.14 defect)
__global__ __launch_bounds__(256) void k_outln(const float* __restrict__ outb,
                                               const float* __restrict__ W,
                                               const float* __restrict__ bias,
                                               const float* __restrict__ qf,
                                               const float* __restrict__ gamma,
                                               const float* __restrict__ beta,
                                               float* __restrict__ y) {
  __shared__ float As[TM * EMB];  // A tile, reused as x tile for LN
  const int tid = threadIdx.x;
  const int row0 = blockIdx.x * TM;
  const float4* Ag = (const float4*)(outb + (size_t)row0 * EMB);
  float4* As4 = (float4*)As;
#pragma unroll
  for (int j = 0; j < 8; ++j) As4[tid + j * 256] = Ag[tid + j * 256];
  __syncthreads();
  const int tcol = tid & 63, trow = tid >> 6;
  float acc[8][4];
#pragma unroll
  for (int r = 0; r < 8; ++r)
#pragma unroll
    for (int s = 0; s < 4; ++s) acc[r][s] = 0.f;
  for (int k4 = 0; k4 < 64; ++k4) {
    float4 a[8];
#pragma unroll
    for (int r = 0; r < 8; ++r) a[r] = As4[(trow * 8 + r) * 64 + k4];
#pragma unroll
    for (int i = 0; i < 4; ++i) {
      const int k = k4 * 4 + i;
      float wv[4];
#pragma unroll
      for (int s = 0; s < 4; ++s) wv[s] = W[k * EMB + tcol + 64 * s];
#pragma unroll
      for (int r = 0; r < 8; ++r) {
        const float av = (i == 0) ? a[r].x : (i == 1) ? a[r].y : (i == 2) ? a[r].z : a[r].w;
#pragma unroll
        for (int s = 0; s < 4; ++s) acc[r][s] = fmaf(av, wv[s], acc[r][s]);
      }
    }
  }
  __syncthreads();
#pragma unroll
  for (int r = 0; r < 8; ++r) {
    const int row = row0 + trow * 8 + r;
#pragma unroll
    for (int s = 0; s < 4; ++s) {
      const int c = tcol + 64 * s;
      As[(trow * 8 + r) * 256 + c] = acc[r][s] + bias[c] + qf[(size_t)row * 256 + c];
    }
  }
  __syncthreads();
  const int lane = tid & 63, wv = tid >> 6;
#pragma unroll
  for (int rr = 0; rr < 8; ++rr) {
    const int r = wv * 8 + rr;
    float s1 = 0.f, s2 = 0.f;
#pragma unroll
    for (int i = 0; i < 4; ++i) {
      const float xv = As[r * 256 + lane + 64 * i];
      s1 += xv; s2 += xv * xv;
    }
#pragma unroll
    for (int o = 32; o >= 1; o >>= 1) {
      s1 += __shfl_xor(s1, o);
      s2 += __shfl_xor(s2, o);
    }
    const float mu = s1 * (1.f / 256.f);
    const float var = s2 * (1.f / 256.f) - mu * mu;
    const float rsig = rsqrtf(var + LN_EPS);
#pragma unroll
    for (int i = 0; i < 4; ++i) {
      const int c = lane + 64 * i;
      const float xv = As[r * 256 + c];
      y[(size_t)(row0 + r) * 256 + c] = (xv - mu) * rsig * gamma[c] + beta[c];
    }
  }
}

extern "C" void kernel_launch(void* const* d_in, const int* in_sizes, int n_in,
                              void* d_out, int out_size, void* d_ws, size_t ws_size,
                              hipStream_t stream) {
  const float* img_feat = (const float*)d_in[0];
  const unsigned char* img_mask = (const unsigned char*)d_in[2];
  const float* vratio = (const float*)d_in[3];
  const float* qf = (const float*)d_in[4];
  const float* qp = (const float*)d_in[5];
  const float* qpts = (const float*)d_in[6];
  const float* Wv = (const float*)d_in[7];
  const float* bv = (const float*)d_in[8];
  const float* Woff = (const float*)d_in[9];
  const float* boff = (const float*)d_in[10];
  const float* Wattn = (const float*)d_in[11];
  const float* battn = (const float*)d_in[12];
  const float* Wout = (const float*)d_in[13];
  const float* bout = (const float*)d_in[14];
  const float* gamma = (const float*)d_in[15];
  const float* beta = (const float*)d_in[16];

  char* ws = (char*)d_ws;
  bf16* V = (bf16*)ws;                                       // 22.3 MB
  bf16* off = (bf16*)(ws + (size_t)NROW * 256 * 2);          // 22.3 MB
  bf16* lg = (bf16*)(ws + (size_t)NROW * 256 * 4);           // 11.1 MB
  unsigned short* wbase =
      (unsigned short*)(ws + (size_t)NROW * 256 * 4 + (size_t)NROW * 128 * 2);
  unsigned short* WvH = wbase;                 // 65536
  unsigned short* WvL = WvH + 65536;           // 65536
  unsigned short* WcatH = WvL + 65536;         // 98304
  unsigned short* WcatL = WcatH + 98304;       // 98304
  float* outb = (float*)d_out;  // fp32 sampled-out scratch (reused as y)

  dim3 blk(256);
  k_trans<<<256, blk, 0, stream>>>(Wv, WvH, WvL, 256);
  k_trans<<<256, blk, 0, stream>>>(Woff, WcatH, WcatL, 256);
  k_trans<<<128, blk, 0, stream>>>(Wattn, WcatH + 256 * 256, WcatL + 256 * 256, 128);
  k_value<<<NROW / 64, blk, 0, stream>>>(img_feat, WvH, WvL, bv, img_mask, V);
  k_offattn<<<NROW / 64, blk, 0, stream>>>(qf, qp, WcatH, WcatL, boff, battn, off, lg);
  k_sample<<<NROW / QB, blk, 0, stream>>>(V, off, lg, qpts, vratio, outb);
  k_outln<<<NROW / TM, blk, 0, stream>>>(outb, Wout, bout, qf, gamma, beta, (float*)d_out);
}

// Round 11
// 263.414 us; speedup vs baseline: 2.1996x; 1.1874x over previous
//
#include <hip/hip_runtime.h>
#include <hip/hip_bf16.h>

#define EMB 256
#define SEQ 21760
#define NB 2
#define NROW (NB * SEQ)   // 43520
#define TM 32
#define QB 8              // queries per k_sample block
#define LN_EPS 1e-5f

typedef __hip_bfloat16 bf16;
typedef short bf16x8 __attribute__((ext_vector_type(8)));
typedef float f32x4 __attribute__((ext_vector_type(4)));

__device__ __forceinline__ unsigned short f2bf(float f) {
  __hip_bfloat16 h = __float2bfloat16(f);
  return *reinterpret_cast<unsigned short*>(&h);
}
__device__ __forceinline__ float bf2f(unsigned short u) {
  return __uint_as_float((unsigned int)u << 16);
}
__device__ __forceinline__ float bflo(unsigned int u) { return __uint_as_float(u << 16); }
__device__ __forceinline__ float bfhi(unsigned int u) { return __uint_as_float(u & 0xffff0000u); }

// ---------------- K0: bf16 transpose of W[k][n] -> Wt[n][k] -----------------
__global__ __launch_bounds__(256) void k_trans(const float* __restrict__ src,
                                               unsigned short* __restrict__ dst, int N) {
  const int n = blockIdx.x, k = threadIdx.x;
  dst[n * 256 + k] = f2bf(src[k * N + n]);
}

// ---------------- K1: V = mask ? 0 : (img_feat @ Wv + bv)  -> bf16 ----------
// BM=64, 4 waves, wave w owns cols [w*64, w*64+64). Plain bf16 MFMA.
// (error analysis: A,W bf16 rounding contributes ~0.007 absmax, under the
//  0.0156 storage floor; MFMA3 compensation proved unnecessary r8 vs r10)
__global__ __launch_bounds__(256) void k_value(const float* __restrict__ A,
                                               const unsigned short* __restrict__ Wt,
                                               const float* __restrict__ bias,
                                               const unsigned char* __restrict__ mask,
                                               bf16* __restrict__ V) {
  __shared__ unsigned short As[64 * 256];  // 32KB, XOR-swizzled
  const int tid = threadIdx.x;
  const int lane = tid & 63, w = tid >> 6;
  const int row0 = blockIdx.x * 64;
#pragma unroll
  for (int it = 0; it < 8; ++it) {
    const int cid = it * 256 + tid;
    const int row = cid >> 5, c = cid & 31;
    const float4* p = (const float4*)(A + (size_t)(row0 + row) * 256 + c * 8);
    const float4 a0 = p[0], a1 = p[1];
    union { unsigned short u[8]; uint4 q; } pk;
    pk.u[0] = f2bf(a0.x); pk.u[1] = f2bf(a0.y); pk.u[2] = f2bf(a0.z); pk.u[3] = f2bf(a0.w);
    pk.u[4] = f2bf(a1.x); pk.u[5] = f2bf(a1.y); pk.u[6] = f2bf(a1.z); pk.u[7] = f2bf(a1.w);
    *(uint4*)((char*)As + row * 512 + ((c * 16) ^ ((row & 7) << 4))) = pk.q;
  }
  __syncthreads();
  const int lg16 = lane >> 4, l16 = lane & 15;
  f32x4 acc[4][4] = {};
#pragma unroll
  for (int kk = 0; kk < 8; ++kk) {
    bf16x8 af[4], bh[4];
#pragma unroll
    for (int mf = 0; mf < 4; ++mf) {
      const int row = mf * 16 + l16;
      af[mf] = *(const bf16x8*)((const char*)As + row * 512 +
                                ((kk * 64 + lg16 * 16) ^ ((row & 7) << 4)));
    }
#pragma unroll
    for (int nf = 0; nf < 4; ++nf) {
      const int col = w * 64 + nf * 16 + l16;
      bh[nf] = *(const bf16x8*)(Wt + (size_t)col * 256 + kk * 32 + lg16 * 8);
    }
#pragma unroll
    for (int mf = 0; mf < 4; ++mf)
#pragma unroll
      for (int nf = 0; nf < 4; ++nf)
        acc[mf][nf] = __builtin_amdgcn_mfma_f32_16x16x32_bf16(af[mf], bh[nf], acc[mf][nf], 0, 0, 0);
  }
#pragma unroll
  for (int mf = 0; mf < 4; ++mf) {
    const int rbase = mf * 16 + lg16 * 4;
    const uchar4 mk = *(const uchar4*)(mask + row0 + rbase);
#pragma unroll
    for (int nf = 0; nf < 4; ++nf) {
      const int col = w * 64 + nf * 16 + l16;
      const float bb = bias[col];
#pragma unroll
      for (int r = 0; r < 4; ++r) {
        const unsigned char m = (r == 0) ? mk.x : (r == 1) ? mk.y : (r == 2) ? mk.z : mk.w;
        const float v = m ? 0.f : (acc[mf][nf][r] + bb);
        V[(size_t)(row0 + rbase + r) * 256 + col] = __float2bfloat16(v);
      }
    }
  }
}

// ---------------- K2: q = qf+qp; [off|lg] = q @ Wcat -> bf16 ----------------
// BM=64, 4 waves, wave w owns cols [w*96, w*96+96) of N=384. Plain bf16 MFMA.
__global__ __launch_bounds__(256) void k_offattn(const float* __restrict__ qf,
                                                 const float* __restrict__ qp,
                                                 const unsigned short* __restrict__ Wt,
                                                 const float* __restrict__ boff,
                                                 const float* __restrict__ battn,
                                                 bf16* __restrict__ off,
                                                 bf16* __restrict__ lg) {
  __shared__ unsigned short As[64 * 256];
  const int tid = threadIdx.x;
  const int lane = tid & 63, w = tid >> 6;
  const int row0 = blockIdx.x * 64;
#pragma unroll
  for (int it = 0; it < 8; ++it) {
    const int cid = it * 256 + tid;
    const int row = cid >> 5, c = cid & 31;
    const float4* pf = (const float4*)(qf + (size_t)(row0 + row) * 256 + c * 8);
    const float4* pp = (const float4*)(qp + (size_t)(row0 + row) * 256 + c * 8);
    const float4 a0 = pf[0], a1 = pf[1], b0 = pp[0], b1 = pp[1];
    union { unsigned short u[8]; uint4 q; } pk;
    pk.u[0] = f2bf(a0.x + b0.x); pk.u[1] = f2bf(a0.y + b0.y);
    pk.u[2] = f2bf(a0.z + b0.z); pk.u[3] = f2bf(a0.w + b0.w);
    pk.u[4] = f2bf(a1.x + b1.x); pk.u[5] = f2bf(a1.y + b1.y);
    pk.u[6] = f2bf(a1.z + b1.z); pk.u[7] = f2bf(a1.w + b1.w);
    *(uint4*)((char*)As + row * 512 + ((c * 16) ^ ((row & 7) << 4))) = pk.q;
  }
  __syncthreads();
  const int lg16 = lane >> 4, l16 = lane & 15;
  f32x4 acc[4][6] = {};
#pragma unroll
  for (int kk = 0; kk < 8; ++kk) {
    bf16x8 af[4], bh[6];
#pragma unroll
    for (int mf = 0; mf < 4; ++mf) {
      const int row = mf * 16 + l16;
      af[mf] = *(const bf16x8*)((const char*)As + row * 512 +
                                ((kk * 64 + lg16 * 16) ^ ((row & 7) << 4)));
    }
#pragma unroll
    for (int nf = 0; nf < 6; ++nf) {
      const int col = w * 96 + nf * 16 + l16;
      bh[nf] = *(const bf16x8*)(Wt + (size_t)col * 256 + kk * 32 + lg16 * 8);
    }
#pragma unroll
    for (int mf = 0; mf < 4; ++mf)
#pragma unroll
      for (int nf = 0; nf < 6; ++nf)
        acc[mf][nf] = __builtin_amdgcn_mfma_f32_16x16x32_bf16(af[mf], bh[nf], acc[mf][nf], 0, 0, 0);
  }
#pragma unroll
  for (int mf = 0; mf < 4; ++mf) {
    const int rbase = row0 + mf * 16 + lg16 * 4;
#pragma unroll
    for (int nf = 0; nf < 6; ++nf) {
      const int col = w * 96 + nf * 16 + l16;
      if (col < 256) {
        const float bb = boff[col];
#pragma unroll
        for (int r = 0; r < 4; ++r)
          off[(size_t)(rbase + r) * 256 + col] = __float2bfloat16(acc[mf][nf][r] + bb);
      } else {
        const float bb = battn[col - 256];
#pragma unroll
        for (int r = 0; r < 4; ++r)
          lg[(size_t)(rbase + r) * 128 + (col - 256)] = __float2bfloat16(acc[mf][nf][r] + bb);
      }
    }
  }
}

// ---------------- K3: softmax + bilinear gather + attn-weighted sum ---------
// QB=8. LDS packed: idx as 4xu16 (uint2), weights as 4xbf16 (uint2) ->
// 18.9KB/block -> 8 blocks/CU (was 4 at 37.4KB). Gather is latency-bound.
__global__ __launch_bounds__(256) void k_sample(const bf16* __restrict__ V,
                                                const bf16* __restrict__ off,
                                                const bf16* __restrict__ lg,
                                                const float* __restrict__ qpts,
                                                const float* __restrict__ vratio,
                                                float* __restrict__ outb) {
  __shared__ uint2 sIdx[QB * 16 * 9];  // [q][i][h(pad 9)] 4x u16 token idx
  __shared__ uint2 sW[QB * 16 * 9];    // 4x bf16 premultiplied weights
  __shared__ float sMax[QB * 8], sInv[QB * 8];
  const int t = threadIdx.x;
  const int row0 = blockIdx.x * QB;

  // ---- phase 0: softmax stats per (q, head)
  if (t < QB * 8) {
    const int q = t >> 3, h = t & 7;
    const int row = row0 + q;
    const uint4* lp = (const uint4*)(lg + (size_t)row * 128 + h * 16);
    uint4 u0 = lp[0], u1 = lp[1];
    float v[16];
    v[0] = bflo(u0.x); v[1] = bfhi(u0.x); v[2] = bflo(u0.y); v[3] = bfhi(u0.y);
    v[4] = bflo(u0.z); v[5] = bfhi(u0.z); v[6] = bflo(u0.w); v[7] = bfhi(u0.w);
    v[8] = bflo(u1.x); v[9] = bfhi(u1.x); v[10] = bflo(u1.y); v[11] = bfhi(u1.y);
    v[12] = bflo(u1.z); v[13] = bfhi(u1.z); v[14] = bflo(u1.w); v[15] = bfhi(u1.w);
    float m = v[0];
#pragma unroll
    for (int i = 1; i < 16; ++i) m = fmaxf(m, v[i]);
    float s = 0.f;
#pragma unroll
    for (int i = 0; i < 16; ++i) s += __expf(v[i] - m);
    sMax[t] = m;
    sInv[t] = 1.f / s;
  }
  __syncthreads();

  // ---- phase 1: per-sample geometry, 4 tasks/thread (QB*128 = 1024 tasks)
  const int Wl_[4] = {128, 64, 32, 16};
  const int st_[4] = {0, 16384, 20480, 21504};
#pragma unroll
  for (int tt = 0; tt < 4; ++tt) {
    const int sid = t + tt * 256;
    const int q = sid >> 7, s = sid & 127;
    const int h = s >> 4, i = s & 15, l = i >> 2;
    const int row = row0 + q;
    const int b = row >= SEQ;  // NB == 2
    const unsigned int u = *(const unsigned int*)(off + (size_t)row * 256 + s * 2);
    const float ox = bflo(u), oy = bfhi(u);
    const float lgv = bf2f(*(const unsigned short*)(lg + (size_t)row * 128 + s));
    const float e = __expf(lgv - sMax[q * 8 + h]) * sInv[q * 8 + h];
    const float px = qpts[(size_t)row * 2], py = qpts[(size_t)row * 2 + 1];
    const float vrx = vratio[b * 8 + l * 2], vry = vratio[b * 8 + l * 2 + 1];
    const int Wl = Wl_[l];
    const float fW = (float)Wl;
    const float x = fmaf(px * vrx, fW, ox) - 0.5f;
    const float y = fmaf(py * vry, fW, oy) - 0.5f;
    const float fx = floorf(x), fy = floorf(y);
    const float wx = x - fx, wy = y - fy;
    const int x0 = (int)fx, y0 = (int)fy;
    const int x1 = x0 + 1, y1 = y0 + 1;
    const int xc0 = min(max(x0, 0), Wl - 1), xc1 = min(max(x1, 0), Wl - 1);
    const int yc0 = min(max(y0, 0), Wl - 1), yc1 = min(max(y1, 0), Wl - 1);
    const float ox0 = (x0 >= 0 && x0 < Wl) ? e : 0.f;   // fold attn weight in
    const float ox1 = (x1 >= 0 && x1 < Wl) ? e : 0.f;
    const float oy0 = (y0 >= 0 && y0 < Wl) ? 1.f : 0.f;
    const float oy1 = (y1 >= 0 && y1 < Wl) ? 1.f : 0.f;
    const int base = b * SEQ + st_[l];   // max token idx 43519 < 65536 -> u16 ok
    const int r0 = base + yc0 * Wl, r1 = base + yc1 * Wl;
    uint2 I, Wp;
    I.x = (unsigned int)(r0 + xc0) | ((unsigned int)(r0 + xc1) << 16);
    I.y = (unsigned int)(r1 + xc0) | ((unsigned int)(r1 + xc1) << 16);
    Wp.x = (unsigned int)f2bf((1.f - wx) * (1.f - wy) * ox0 * oy0) |
           ((unsigned int)f2bf(wx * (1.f - wy) * ox1 * oy0) << 16);
    Wp.y = (unsigned int)f2bf((1.f - wx) * wy * ox0 * oy1) |
           ((unsigned int)f2bf(wx * wy * ox1 * oy1) << 16);
    sIdx[(q * 16 + i) * 9 + h] = I;
    sW[(q * 16 + i) * 9 + h] = Wp;
  }
  __syncthreads();

  // ---- phase 2: gather + weighted accumulate; thread = (q, h, 8 channels)
  const int q = t >> 5, sub = t & 31;
  const int h = sub >> 2, dg = sub & 3;
  const int row = row0 + q;
  const bf16* vb = V + h * 32 + dg * 8;
  float a0 = 0.f, a1 = 0.f, a2 = 0.f, a3 = 0.f;
  float a4 = 0.f, a5 = 0.f, a6 = 0.f, a7 = 0.f;
#pragma unroll
  for (int i = 0; i < 16; ++i) {
    const uint2 I = sIdx[(q * 16 + i) * 9 + h];
    const uint2 Wp = sW[(q * 16 + i) * 9 + h];
    const int i0 = I.x & 0xffff, i1 = I.x >> 16;
    const int i2 = I.y & 0xffff, i3 = I.y >> 16;
    const float w0 = bflo(Wp.x), w1 = bfhi(Wp.x);
    const float w2 = bflo(Wp.y), w3 = bfhi(Wp.y);
    {
      const uint4 u = *(const uint4*)(vb + (size_t)i0 * 256);
      a0 = fmaf(w0, bflo(u.x), a0); a1 = fmaf(w0, bfhi(u.x), a1);
      a2 = fmaf(w0, bflo(u.y), a2); a3 = fmaf(w0, bfhi(u.y), a3);
      a4 = fmaf(w0, bflo(u.z), a4); a5 = fmaf(w0, bfhi(u.z), a5);
      a6 = fmaf(w0, bflo(u.w), a6); a7 = fmaf(w0, bfhi(u.w), a7);
    }
    {
      const uint4 u = *(const uint4*)(vb + (size_t)i1 * 256);
      a0 = fmaf(w1, bflo(u.x), a0); a1 = fmaf(w1, bfhi(u.x), a1);
      a2 = fmaf(w1, bflo(u.y), a2); a3 = fmaf(w1, bfhi(u.y), a3);
      a4 = fmaf(w1, bflo(u.z), a4); a5 = fmaf(w1, bfhi(u.z), a5);
      a6 = fmaf(w1, bflo(u.w), a6); a7 = fmaf(w1, bfhi(u.w), a7);
    }
    {
      const uint4 u = *(const uint4*)(vb + (size_t)i2 * 256);
      a0 = fmaf(w2, bflo(u.x), a0); a1 = fmaf(w2, bfhi(u.x), a1);
      a2 = fmaf(w2, bflo(u.y), a2); a3 = fmaf(w2, bfhi(u.y), a3);
      a4 = fmaf(w2, bflo(u.z), a4); a5 = fmaf(w2, bfhi(u.z), a5);
      a6 = fmaf(w2, bflo(u.w), a6); a7 = fmaf(w2, bfhi(u.w), a7);
    }
    {
      const uint4 u = *(const uint4*)(vb + (size_t)i3 * 256);
      a0 = fmaf(w3, bflo(u.x), a0); a1 = fmaf(w3, bfhi(u.x), a1);
      a2 = fmaf(w3, bflo(u.y), a2); a3 = fmaf(w3, bfhi(u.y), a3);
      a4 = fmaf(w3, bflo(u.z), a4); a5 = fmaf(w3, bfhi(u.z), a5);
      a6 = fmaf(w3, bflo(u.w), a6); a7 = fmaf(w3, bfhi(u.w), a7);
    }
  }
  float4 o0, o1;
  o0.x = a0; o0.y = a1; o0.z = a2; o0.w = a3;
  o1.x = a4; o1.y = a5; o1.z = a6; o1.w = a7;
  float* op = outb + (size_t)row * 256 + h * 32 + dg * 8;
  *(float4*)op = o0;
  *(float4*)(op + 4) = o1;
}

// ---------------- K4: update = outb @ Wout + bout; LN(qf + update) ----------
// (byte-identical to round 10: fp32 vector-ALU GEMM — PROVEN; the MFMA
//  variant of this kernel carries an unexplained ~0.14 defect, quarantined)
__global__ __launch_bounds__(256) void k_outln(const float* __restrict__ outb,
                                               const float* __restrict__ W,
                                               const float* __restrict__ bias,
                                               const float* __restrict__ qf,
                                               const float* __restrict__ gamma,
                                               const float* __restrict__ beta,
                                               float* __restrict__ y) {
  __shared__ float As[TM * EMB];  // A tile, reused as x tile for LN
  const int tid = threadIdx.x;
  const int row0 = blockIdx.x * TM;
  const float4* Ag = (const float4*)(outb + (size_t)row0 * EMB);
  float4* As4 = (float4*)As;
#pragma unroll
  for (int j = 0; j < 8; ++j) As4[tid + j * 256] = Ag[tid + j * 256];
  __syncthreads();
  const int tcol = tid & 63, trow = tid >> 6;
  float acc[8][4];
#pragma unroll
  for (int r = 0; r < 8; ++r)
#pragma unroll
    for (int s = 0; s < 4; ++s) acc[r][s] = 0.f;
  for (int k4 = 0; k4 < 64; ++k4) {
    float4 a[8];
#pragma unroll
    for (int r = 0; r < 8; ++r) a[r] = As4[(trow * 8 + r) * 64 + k4];
#pragma unroll
    for (int i = 0; i < 4; ++i) {
      const int k = k4 * 4 + i;
      float wv[4];
#pragma unroll
      for (int s = 0; s < 4; ++s) wv[s] = W[k * EMB + tcol + 64 * s];
#pragma unroll
      for (int r = 0; r < 8; ++r) {
        const float av = (i == 0) ? a[r].x : (i == 1) ? a[r].y : (i == 2) ? a[r].z : a[r].w;
#pragma unroll
        for (int s = 0; s < 4; ++s) acc[r][s] = fmaf(av, wv[s], acc[r][s]);
      }
    }
  }
  __syncthreads();
#pragma unroll
  for (int r = 0; r < 8; ++r) {
    const int row = row0 + trow * 8 + r;
#pragma unroll
    for (int s = 0; s < 4; ++s) {
      const int c = tcol + 64 * s;
      As[(trow * 8 + r) * 256 + c] = acc[r][s] + bias[c] + qf[(size_t)row * 256 + c];
    }
  }
  __syncthreads();
  const int lane = tid & 63, wv = tid >> 6;
#pragma unroll
  for (int rr = 0; rr < 8; ++rr) {
    const int r = wv * 8 + rr;
    float s1 = 0.f, s2 = 0.f;
#pragma unroll
    for (int i = 0; i < 4; ++i) {
      const float xv = As[r * 256 + lane + 64 * i];
      s1 += xv; s2 += xv * xv;
    }
#pragma unroll
    for (int o = 32; o >= 1; o >>= 1) {
      s1 += __shfl_xor(s1, o);
      s2 += __shfl_xor(s2, o);
    }
    const float mu = s1 * (1.f / 256.f);
    const float var = s2 * (1.f / 256.f) - mu * mu;
    const float rsig = rsqrtf(var + LN_EPS);
#pragma unroll
    for (int i = 0; i < 4; ++i) {
      const int c = lane + 64 * i;
      const float xv = As[r * 256 + c];
      y[(size_t)(row0 + r) * 256 + c] = (xv - mu) * rsig * gamma[c] + beta[c];
    }
  }
}

extern "C" void kernel_launch(void* const* d_in, const int* in_sizes, int n_in,
                              void* d_out, int out_size, void* d_ws, size_t ws_size,
                              hipStream_t stream) {
  const float* img_feat = (const float*)d_in[0];
  const unsigned char* img_mask = (const unsigned char*)d_in[2];
  const float* vratio = (const float*)d_in[3];
  const float* qf = (const float*)d_in[4];
  const float* qp = (const float*)d_in[5];
  const float* qpts = (const float*)d_in[6];
  const float* Wv = (const float*)d_in[7];
  const float* bv = (const float*)d_in[8];
  const float* Woff = (const float*)d_in[9];
  const float* boff = (const float*)d_in[10];
  const float* Wattn = (const float*)d_in[11];
  const float* battn = (const float*)d_in[12];
  const float* Wout = (const float*)d_in[13];
  const float* bout = (const float*)d_in[14];
  const float* gamma = (const float*)d_in[15];
  const float* beta = (const float*)d_in[16];

  char* ws = (char*)d_ws;
  bf16* V = (bf16*)ws;                                       // 22.3 MB
  bf16* off = (bf16*)(ws + (size_t)NROW * 256 * 2);          // 22.3 MB
  bf16* lg = (bf16*)(ws + (size_t)NROW * 256 * 4);           // 11.1 MB
  unsigned short* wbase =
      (unsigned short*)(ws + (size_t)NROW * 256 * 4 + (size_t)NROW * 128 * 2);
  unsigned short* WvT = wbase;              // 65536
  unsigned short* WcatT = WvT + 65536;      // 98304
  float* outb = (float*)d_out;  // fp32 sampled-out scratch (reused as y)

  dim3 blk(256);
  k_trans<<<256, blk, 0, stream>>>(Wv, WvT, 256);
  k_trans<<<256, blk, 0, stream>>>(Woff, WcatT, 256);
  k_trans<<<128, blk, 0, stream>>>(Wattn, WcatT + 256 * 256, 128);
  k_value<<<NROW / 64, blk, 0, stream>>>(img_feat, WvT, bv, img_mask, V);
  k_offattn<<<NROW / 64, blk, 0, stream>>>(qf, qp, WcatT, boff, battn, off, lg);
  k_sample<<<NROW / QB, blk, 0, stream>>>(V, off, lg, qpts, vratio, outb);
  k_outln<<<NROW / TM, blk, 0, stream>>>(outb, Wout, bout, qf, gamma, beta, (float*)d_out);
}

// Round 13
// 261.321 us; speedup vs baseline: 2.2172x; 1.0080x over previous
//
#include <hip/hip_runtime.h>
#include <hip/hip_bf16.h>

#define EMB 256
#define SEQ 21760
#define NB 2
#define NROW (NB * SEQ)   // 43520
#define TM 32
#define QB 8              // queries per k_sample block
#define LN_EPS 1e-5f

typedef __hip_bfloat16 bf16;
typedef short bf16x8 __attribute__((ext_vector_type(8)));
typedef float f32x4 __attribute__((ext_vector_type(4)));

__device__ __forceinline__ unsigned short f2bf(float f) {
  __hip_bfloat16 h = __float2bfloat16(f);
  return *reinterpret_cast<unsigned short*>(&h);
}
__device__ __forceinline__ float bf2f(unsigned short u) {
  return __uint_as_float((unsigned int)u << 16);
}
__device__ __forceinline__ float bflo(unsigned int u) { return __uint_as_float(u << 16); }
__device__ __forceinline__ float bfhi(unsigned int u) { return __uint_as_float(u & 0xffff0000u); }

// ---------------- K0: bf16 transpose of W[k][n] -> Wt[n][k] -----------------
__global__ __launch_bounds__(256) void k_trans(const float* __restrict__ src,
                                               unsigned short* __restrict__ dst, int N) {
  const int n = blockIdx.x, k = threadIdx.x;
  dst[n * 256 + k] = f2bf(src[k * N + n]);
}

// ---------------- K1: V = mask ? 0 : (img_feat @ Wv + bv)  -> bf16 ----------
// (byte-identical to round 11 — proven at fp32 floor)
__global__ __launch_bounds__(256) void k_value(const float* __restrict__ A,
                                               const unsigned short* __restrict__ Wt,
                                               const float* __restrict__ bias,
                                               const unsigned char* __restrict__ mask,
                                               bf16* __restrict__ V) {
  __shared__ unsigned short As[64 * 256];  // 32KB, XOR-swizzled
  const int tid = threadIdx.x;
  const int lane = tid & 63, w = tid >> 6;
  const int row0 = blockIdx.x * 64;
#pragma unroll
  for (int it = 0; it < 8; ++it) {
    const int cid = it * 256 + tid;
    const int row = cid >> 5, c = cid & 31;
    const float4* p = (const float4*)(A + (size_t)(row0 + row) * 256 + c * 8);
    const float4 a0 = p[0], a1 = p[1];
    union { unsigned short u[8]; uint4 q; } pk;
    pk.u[0] = f2bf(a0.x); pk.u[1] = f2bf(a0.y); pk.u[2] = f2bf(a0.z); pk.u[3] = f2bf(a0.w);
    pk.u[4] = f2bf(a1.x); pk.u[5] = f2bf(a1.y); pk.u[6] = f2bf(a1.z); pk.u[7] = f2bf(a1.w);
    *(uint4*)((char*)As + row * 512 + ((c * 16) ^ ((row & 7) << 4))) = pk.q;
  }
  __syncthreads();
  const int lg16 = lane >> 4, l16 = lane & 15;
  f32x4 acc[4][4] = {};
#pragma unroll
  for (int kk = 0; kk < 8; ++kk) {
    bf16x8 af[4], bh[4];
#pragma unroll
    for (int mf = 0; mf < 4; ++mf) {
      const int row = mf * 16 + l16;
      af[mf] = *(const bf16x8*)((const char*)As + row * 512 +
                                ((kk * 64 + lg16 * 16) ^ ((row & 7) << 4)));
    }
#pragma unroll
    for (int nf = 0; nf < 4; ++nf) {
      const int col = w * 64 + nf * 16 + l16;
      bh[nf] = *(const bf16x8*)(Wt + (size_t)col * 256 + kk * 32 + lg16 * 8);
    }
#pragma unroll
    for (int mf = 0; mf < 4; ++mf)
#pragma unroll
      for (int nf = 0; nf < 4; ++nf)
        acc[mf][nf] = __builtin_amdgcn_mfma_f32_16x16x32_bf16(af[mf], bh[nf], acc[mf][nf], 0, 0, 0);
  }
#pragma unroll
  for (int mf = 0; mf < 4; ++mf) {
    const int rbase = mf * 16 + lg16 * 4;
    const uchar4 mk = *(const uchar4*)(mask + row0 + rbase);
#pragma unroll
    for (int nf = 0; nf < 4; ++nf) {
      const int col = w * 64 + nf * 16 + l16;
      const float bb = bias[col];
#pragma unroll
      for (int r = 0; r < 4; ++r) {
        const unsigned char m = (r == 0) ? mk.x : (r == 1) ? mk.y : (r == 2) ? mk.z : mk.w;
        const float v = m ? 0.f : (acc[mf][nf][r] + bb);
        V[(size_t)(row0 + rbase + r) * 256 + col] = __float2bfloat16(v);
      }
    }
  }
}

// ---------------- K2: q = qf+qp; [off|lg] = q @ Wcat -> bf16 ----------------
// (byte-identical to round 11 — proven)
__global__ __launch_bounds__(256) void k_offattn(const float* __restrict__ qf,
                                                 const float* __restrict__ qp,
                                                 const unsigned short* __restrict__ Wt,
                                                 const float* __restrict__ boff,
                                                 const float* __restrict__ battn,
                                                 bf16* __restrict__ off,
                                                 bf16* __restrict__ lg) {
  __shared__ unsigned short As[64 * 256];
  const int tid = threadIdx.x;
  const int lane = tid & 63, w = tid >> 6;
  const int row0 = blockIdx.x * 64;
#pragma unroll
  for (int it = 0; it < 8; ++it) {
    const int cid = it * 256 + tid;
    const int row = cid >> 5, c = cid & 31;
    const float4* pf = (const float4*)(qf + (size_t)(row0 + row) * 256 + c * 8);
    const float4* pp = (const float4*)(qp + (size_t)(row0 + row) * 256 + c * 8);
    const float4 a0 = pf[0], a1 = pf[1], b0 = pp[0], b1 = pp[1];
    union { unsigned short u[8]; uint4 q; } pk;
    pk.u[0] = f2bf(a0.x + b0.x); pk.u[1] = f2bf(a0.y + b0.y);
    pk.u[2] = f2bf(a0.z + b0.z); pk.u[3] = f2bf(a0.w + b0.w);
    pk.u[4] = f2bf(a1.x + b1.x); pk.u[5] = f2bf(a1.y + b1.y);
    pk.u[6] = f2bf(a1.z + b1.z); pk.u[7] = f2bf(a1.w + b1.w);
    *(uint4*)((char*)As + row * 512 + ((c * 16) ^ ((row & 7) << 4))) = pk.q;
  }
  __syncthreads();
  const int lg16 = lane >> 4, l16 = lane & 15;
  f32x4 acc[4][6] = {};
#pragma unroll
  for (int kk = 0; kk < 8; ++kk) {
    bf16x8 af[4], bh[6];
#pragma unroll
    for (int mf = 0; mf < 4; ++mf) {
      const int row = mf * 16 + l16;
      af[mf] = *(const bf16x8*)((const char*)As + row * 512 +
                                ((kk * 64 + lg16 * 16) ^ ((row & 7) << 4)));
    }
#pragma unroll
    for (int nf = 0; nf < 6; ++nf) {
      const int col = w * 96 + nf * 16 + l16;
      bh[nf] = *(const bf16x8*)(Wt + (size_t)col * 256 + kk * 32 + lg16 * 8);
    }
#pragma unroll
    for (int mf = 0; mf < 4; ++mf)
#pragma unroll
      for (int nf = 0; nf < 6; ++nf)
        acc[mf][nf] = __builtin_amdgcn_mfma_f32_16x16x32_bf16(af[mf], bh[nf], acc[mf][nf], 0, 0, 0);
  }
#pragma unroll
  for (int mf = 0; mf < 4; ++mf) {
    const int rbase = row0 + mf * 16 + lg16 * 4;
#pragma unroll
    for (int nf = 0; nf < 6; ++nf) {
      const int col = w * 96 + nf * 16 + l16;
      if (col < 256) {
        const float bb = boff[col];
#pragma unroll
        for (int r = 0; r < 4; ++r)
          off[(size_t)(rbase + r) * 256 + col] = __float2bfloat16(acc[mf][nf][r] + bb);
      } else {
        const float bb = battn[col - 256];
#pragma unroll
        for (int r = 0; r < 4; ++r)
          lg[(size_t)(rbase + r) * 128 + (col - 256)] = __float2bfloat16(acc[mf][nf][r] + bb);
      }
    }
  }
}

// ---------------- K3: softmax + bilinear gather + attn-weighted sum ---------
// (byte-identical to round 11 — proven)
__global__ __launch_bounds__(256) void k_sample(const bf16* __restrict__ V,
                                                const bf16* __restrict__ off,
                                                const bf16* __restrict__ lg,
                                                const float* __restrict__ qpts,
                                                const float* __restrict__ vratio,
                                                float* __restrict__ outb) {
  __shared__ uint2 sIdx[QB * 16 * 9];  // [q][i][h(pad 9)] 4x u16 token idx
  __shared__ uint2 sW[QB * 16 * 9];    // 4x bf16 premultiplied weights
  __shared__ float sMax[QB * 8], sInv[QB * 8];
  const int t = threadIdx.x;
  const int row0 = blockIdx.x * QB;

  if (t < QB * 8) {
    const int q = t >> 3, h = t & 7;
    const int row = row0 + q;
    const uint4* lp = (const uint4*)(lg + (size_t)row * 128 + h * 16);
    uint4 u0 = lp[0], u1 = lp[1];
    float v[16];
    v[0] = bflo(u0.x); v[1] = bfhi(u0.x); v[2] = bflo(u0.y); v[3] = bfhi(u0.y);
    v[4] = bflo(u0.z); v[5] = bfhi(u0.z); v[6] = bflo(u0.w); v[7] = bfhi(u0.w);
    v[8] = bflo(u1.x); v[9] = bfhi(u1.x); v[10] = bflo(u1.y); v[11] = bfhi(u1.y);
    v[12] = bflo(u1.z); v[13] = bfhi(u1.z); v[14] = bflo(u1.w); v[15] = bfhi(u1.w);
    float m = v[0];
#pragma unroll
    for (int i = 1; i < 16; ++i) m = fmaxf(m, v[i]);
    float s = 0.f;
#pragma unroll
    for (int i = 0; i < 16; ++i) s += __expf(v[i] - m);
    sMax[t] = m;
    sInv[t] = 1.f / s;
  }
  __syncthreads();

  const int Wl_[4] = {128, 64, 32, 16};
  const int st_[4] = {0, 16384, 20480, 21504};
#pragma unroll
  for (int tt = 0; tt < 4; ++tt) {
    const int sid = t + tt * 256;
    const int q = sid >> 7, s = sid & 127;
    const int h = s >> 4, i = s & 15, l = i >> 2;
    const int row = row0 + q;
    const int b = row >= SEQ;  // NB == 2
    const unsigned int u = *(const unsigned int*)(off + (size_t)row * 256 + s * 2);
    const float ox = bflo(u), oy = bfhi(u);
    const float lgv = bf2f(*(const unsigned short*)(lg + (size_t)row * 128 + s));
    const float e = __expf(lgv - sMax[q * 8 + h]) * sInv[q * 8 + h];
    const float px = qpts[(size_t)row * 2], py = qpts[(size_t)row * 2 + 1];
    const float vrx = vratio[b * 8 + l * 2], vry = vratio[b * 8 + l * 2 + 1];
    const int Wl = Wl_[l];
    const float fW = (float)Wl;
    const float x = fmaf(px * vrx, fW, ox) - 0.5f;
    const float y = fmaf(py * vry, fW, oy) - 0.5f;
    const float fx = floorf(x), fy = floorf(y);
    const float wx = x - fx, wy = y - fy;
    const int x0 = (int)fx, y0 = (int)fy;
    const int x1 = x0 + 1, y1 = y0 + 1;
    const int xc0 = min(max(x0, 0), Wl - 1), xc1 = min(max(x1, 0), Wl - 1);
    const int yc0 = min(max(y0, 0), Wl - 1), yc1 = min(max(y1, 0), Wl - 1);
    const float ox0 = (x0 >= 0 && x0 < Wl) ? e : 0.f;   // fold attn weight in
    const float ox1 = (x1 >= 0 && x1 < Wl) ? e : 0.f;
    const float oy0 = (y0 >= 0 && y0 < Wl) ? 1.f : 0.f;
    const float oy1 = (y1 >= 0 && y1 < Wl) ? 1.f : 0.f;
    const int base = b * SEQ + st_[l];   // max token idx 43519 < 65536 -> u16 ok
    const int r0 = base + yc0 * Wl, r1 = base + yc1 * Wl;
    uint2 I, Wp;
    I.x = (unsigned int)(r0 + xc0) | ((unsigned int)(r0 + xc1) << 16);
    I.y = (unsigned int)(r1 + xc0) | ((unsigned int)(r1 + xc1) << 16);
    Wp.x = (unsigned int)f2bf((1.f - wx) * (1.f - wy) * ox0 * oy0) |
           ((unsigned int)f2bf(wx * (1.f - wy) * ox1 * oy0) << 16);
    Wp.y = (unsigned int)f2bf((1.f - wx) * wy * ox0 * oy1) |
           ((unsigned int)f2bf(wx * wy * ox1 * oy1) << 16);
    sIdx[(q * 16 + i) * 9 + h] = I;
    sW[(q * 16 + i) * 9 + h] = Wp;
  }
  __syncthreads();

  const int q = t >> 5, sub = t & 31;
  const int h = sub >> 2, dg = sub & 3;
  const int row = row0 + q;
  const bf16* vb = V + h * 32 + dg * 8;
  float a0 = 0.f, a1 = 0.f, a2 = 0.f, a3 = 0.f;
  float a4 = 0.f, a5 = 0.f, a6 = 0.f, a7 = 0.f;
#pragma unroll
  for (int i = 0; i < 16; ++i) {
    const uint2 I = sIdx[(q * 16 + i) * 9 + h];
    const uint2 Wp = sW[(q * 16 + i) * 9 + h];
    const int i0 = I.x & 0xffff, i1 = I.x >> 16;
    const int i2 = I.y & 0xffff, i3 = I.y >> 16;
    const float w0 = bflo(Wp.x), w1 = bfhi(Wp.x);
    const float w2 = bflo(Wp.y), w3 = bfhi(Wp.y);
    {
      const uint4 u = *(const uint4*)(vb + (size_t)i0 * 256);
      a0 = fmaf(w0, bflo(u.x), a0); a1 = fmaf(w0, bfhi(u.x), a1);
      a2 = fmaf(w0, bflo(u.y), a2); a3 = fmaf(w0, bfhi(u.y), a3);
      a4 = fmaf(w0, bflo(u.z), a4); a5 = fmaf(w0, bfhi(u.z), a5);
      a6 = fmaf(w0, bflo(u.w), a6); a7 = fmaf(w0, bfhi(u.w), a7);
    }
    {
      const uint4 u = *(const uint4*)(vb + (size_t)i1 * 256);
      a0 = fmaf(w1, bflo(u.x), a0); a1 = fmaf(w1, bfhi(u.x), a1);
      a2 = fmaf(w1, bflo(u.y), a2); a3 = fmaf(w1, bfhi(u.y), a3);
      a4 = fmaf(w1, bflo(u.z), a4); a5 = fmaf(w1, bfhi(u.z), a5);
      a6 = fmaf(w1, bflo(u.w), a6); a7 = fmaf(w1, bfhi(u.w), a7);
    }
    {
      const uint4 u = *(const uint4*)(vb + (size_t)i2 * 256);
      a0 = fmaf(w2, bflo(u.x), a0); a1 = fmaf(w2, bfhi(u.x), a1);
      a2 = fmaf(w2, bflo(u.y), a2); a3 = fmaf(w2, bfhi(u.y), a3);
      a4 = fmaf(w2, bflo(u.z), a4); a5 = fmaf(w2, bfhi(u.z), a5);
      a6 = fmaf(w2, bflo(u.w), a6); a7 = fmaf(w2, bfhi(u.w), a7);
    }
    {
      const uint4 u = *(const uint4*)(vb + (size_t)i3 * 256);
      a0 = fmaf(w3, bflo(u.x), a0); a1 = fmaf(w3, bfhi(u.x), a1);
      a2 = fmaf(w3, bflo(u.y), a2); a3 = fmaf(w3, bfhi(u.y), a3);
      a4 = fmaf(w3, bflo(u.z), a4); a5 = fmaf(w3, bfhi(u.z), a5);
      a6 = fmaf(w3, bflo(u.w), a6); a7 = fmaf(w3, bfhi(u.w), a7);
    }
  }
  float4 o0, o1;
  o0.x = a0; o0.y = a1; o0.z = a2; o0.w = a3;
  o1.x = a4; o1.y = a5; o1.z = a6; o1.w = a7;
  float* op = outb + (size_t)row * 256 + h * 32 + dg * 8;
  *(float4*)op = o0;
  *(float4*)(op + 4) = o1;
}

// ---------------- K4: update = outb @ Wout + bout; LN(qf + update) ----------
// fp32 vector GEMM (MFMA variant quarantined: 6/6 fails, unexplained ~0.14).
// Change vs round 11: thread owns 4 CONTIGUOUS cols (tcol*4..+4) so W loads
// are float4/dwordx4 (256 instead of 1024 scalar loads per thread).
// Per-output FMA order unchanged -> bit-exact vs round 11.
__global__ __launch_bounds__(256) void k_outln(const float* __restrict__ outb,
                                               const float* __restrict__ W,
                                               const float* __restrict__ bias,
                                               const float* __restrict__ qf,
                                               const float* __restrict__ gamma,
                                               const float* __restrict__ beta,
                                               float* __restrict__ y) {
  __shared__ float As[TM * EMB];  // A tile, reused as x tile for LN
  const int tid = threadIdx.x;
  const int row0 = blockIdx.x * TM;
  const float4* Ag = (const float4*)(outb + (size_t)row0 * EMB);
  float4* As4 = (float4*)As;
#pragma unroll
  for (int j = 0; j < 8; ++j) As4[tid + j * 256] = Ag[tid + j * 256];
  __syncthreads();
  const int tcol = tid & 63, trow = tid >> 6;
  float acc[8][4];
#pragma unroll
  for (int r = 0; r < 8; ++r)
#pragma unroll
    for (int s = 0; s < 4; ++s) acc[r][s] = 0.f;
  for (int k4 = 0; k4 < 64; ++k4) {
    float4 a[8];
#pragma unroll
    for (int r = 0; r < 8; ++r) a[r] = As4[(trow * 8 + r) * 64 + k4];
#pragma unroll
    for (int i = 0; i < 4; ++i) {
      const int k = k4 * 4 + i;
      const float4 wv = *(const float4*)(W + k * 256 + tcol * 4);
#pragma unroll
      for (int r = 0; r < 8; ++r) {
        const float av = (i == 0) ? a[r].x : (i == 1) ? a[r].y : (i == 2) ? a[r].z : a[r].w;
        acc[r][0] = fmaf(av, wv.x, acc[r][0]);
        acc[r][1] = fmaf(av, wv.y, acc[r][1]);
        acc[r][2] = fmaf(av, wv.z, acc[r][2]);
        acc[r][3] = fmaf(av, wv.w, acc[r][3]);
      }
    }
  }
  __syncthreads();  // everyone done reading A tile; reuse As as x tile
#pragma unroll
  for (int r = 0; r < 8; ++r) {
    const int row = row0 + trow * 8 + r;
    const int c = tcol * 4;
    const float4 qv = *(const float4*)(qf + (size_t)row * 256 + c);
    const float4 bb = *(const float4*)(bias + c);
    float4 xv;
    xv.x = acc[r][0] + bb.x + qv.x;
    xv.y = acc[r][1] + bb.y + qv.y;
    xv.z = acc[r][2] + bb.z + qv.z;
    xv.w = acc[r][3] + bb.w + qv.w;
    *(float4*)&As[(trow * 8 + r) * 256 + c] = xv;
  }
  __syncthreads();
  const int lane = tid & 63, wv_ = tid >> 6;
#pragma unroll
  for (int rr = 0; rr < 8; ++rr) {
    const int r = wv_ * 8 + rr;
    float s1 = 0.f, s2 = 0.f;
#pragma unroll
    for (int i = 0; i < 4; ++i) {
      const float xv = As[r * 256 + lane + 64 * i];
      s1 += xv; s2 += xv * xv;
    }
#pragma unroll
    for (int o = 32; o >= 1; o >>= 1) {
      s1 += __shfl_xor(s1, o);
      s2 += __shfl_xor(s2, o);
    }
    const float mu = s1 * (1.f / 256.f);
    const float var = s2 * (1.f / 256.f) - mu * mu;
    const float rsig = rsqrtf(var + LN_EPS);
#pragma unroll
    for (int i = 0; i < 4; ++i) {
      const int c = lane + 64 * i;
      const float xv = As[r * 256 + c];
      y[(size_t)(row0 + r) * 256 + c] = (xv - mu) * rsig * gamma[c] + beta[c];
    }
  }
}

extern "C" void kernel_launch(void* const* d_in, const int* in_sizes, int n_in,
                              void* d_out, int out_size, void* d_ws, size_t ws_size,
                              hipStream_t stream) {
  const float* img_feat = (const float*)d_in[0];
  const unsigned char* img_mask = (const unsigned char*)d_in[2];
  const float* vratio = (const float*)d_in[3];
  const float* qf = (const float*)d_in[4];
  const float* qp = (const float*)d_in[5];
  const float* qpts = (const float*)d_in[6];
  const float* Wv = (const float*)d_in[7];
  const float* bv = (const float*)d_in[8];
  const float* Woff = (const float*)d_in[9];
  const float* boff = (const float*)d_in[10];
  const float* Wattn = (const float*)d_in[11];
  const float* battn = (const float*)d_in[12];
  const float* Wout = (const float*)d_in[13];
  const float* bout = (const float*)d_in[14];
  const float* gamma = (const float*)d_in[15];
  const float* beta = (const float*)d_in[16];

  char* ws = (char*)d_ws;
  bf16* V = (bf16*)ws;                                       // 22.3 MB
  bf16* off = (bf16*)(ws + (size_t)NROW * 256 * 2);          // 22.3 MB
  bf16* lg = (bf16*)(ws + (size_t)NROW * 256 * 4);           // 11.1 MB
  unsigned short* wbase =
      (unsigned short*)(ws + (size_t)NROW * 256 * 4 + (size_t)NROW * 128 * 2);
  unsigned short* WvT = wbase;              // 65536
  unsigned short* WcatT = WvT + 65536;      // 98304
  float* outb = (float*)d_out;  // fp32 sampled-out scratch (reused as y)

  dim3 blk(256);
  k_trans<<<256, blk, 0, stream>>>(Wv, WvT, 256);
  k_trans<<<256, blk, 0, stream>>>(Woff, WcatT, 256);
  k_trans<<<128, blk, 0, stream>>>(Wattn, WcatT + 256 * 256, 128);
  k_value<<<NROW / 64, blk, 0, stream>>>(img_feat, WvT, bv, img_mask, V);
  k_offattn<<<NROW / 64, blk, 0, stream>>>(qf, qp, WcatT, boff, battn, off, lg);
  k_sample<<<NROW / QB, blk, 0, stream>>>(V, off, lg, qpts, vratio, outb);
  k_outln<<<NROW / TM, blk, 0, stream>>>(outb, Wout, bout, qf, gamma, beta, (float*)d_out);
}

// Round 15
// 217.991 us; speedup vs baseline: 2.6579x; 1.1988x over previous
//
#include <hip/hip_runtime.h>
#include <hip/hip_bf16.h>

#define EMB 256
#define SEQ 21760
#define NB 2
#define NROW (NB * SEQ)   // 43520
#define QB 8              // queries per k_sample block
#define LN_EPS 1e-5f

typedef __hip_bfloat16 bf16;
typedef short bf16x8 __attribute__((ext_vector_type(8)));
typedef float f32x4 __attribute__((ext_vector_type(4)));

__device__ __forceinline__ unsigned short f2bf(float f) {
  __hip_bfloat16 h = __float2bfloat16(f);
  return *reinterpret_cast<unsigned short*>(&h);
}
__device__ __forceinline__ float bf2f(unsigned short u) {
  return __uint_as_float((unsigned int)u << 16);
}
__device__ __forceinline__ float bflo(unsigned int u) { return __uint_as_float(u << 16); }
__device__ __forceinline__ float bfhi(unsigned int u) { return __uint_as_float(u & 0xffff0000u); }

// ---------------- K0: bf16 transpose of W[k][n] -> Wt[n][k] -----------------
__global__ __launch_bounds__(256) void k_trans(const float* __restrict__ src,
                                               unsigned short* __restrict__ dst, int N) {
  const int n = blockIdx.x, k = threadIdx.x;
  dst[n * 256 + k] = f2bf(src[k * N + n]);
}

// ---------------- K1: V = mask ? 0 : (A @ Wt + bias)  -> bf16 ---------------
// (byte-identical to rounds 11/13/14 — proven at fp32 floor)
__global__ __launch_bounds__(256) void k_value(const float* __restrict__ A,
                                               const unsigned short* __restrict__ Wt,
                                               const float* __restrict__ bias,
                                               const unsigned char* __restrict__ mask,
                                               bf16* __restrict__ V) {
  __shared__ unsigned short As[64 * 256];  // 32KB, XOR-swizzled
  const int tid = threadIdx.x;
  const int lane = tid & 63, w = tid >> 6;
  const int row0 = blockIdx.x * 64;
#pragma unroll
  for (int it = 0; it < 8; ++it) {
    const int cid = it * 256 + tid;
    const int row = cid >> 5, c = cid & 31;
    const float4* p = (const float4*)(A + (size_t)(row0 + row) * 256 + c * 8);
    const float4 a0 = p[0], a1 = p[1];
    union { unsigned short u[8]; uint4 q; } pk;
    pk.u[0] = f2bf(a0.x); pk.u[1] = f2bf(a0.y); pk.u[2] = f2bf(a0.z); pk.u[3] = f2bf(a0.w);
    pk.u[4] = f2bf(a1.x); pk.u[5] = f2bf(a1.y); pk.u[6] = f2bf(a1.z); pk.u[7] = f2bf(a1.w);
    *(uint4*)((char*)As + row * 512 + ((c * 16) ^ ((row & 7) << 4))) = pk.q;
  }
  __syncthreads();
  const int lg16 = lane >> 4, l16 = lane & 15;
  f32x4 acc[4][4] = {};
#pragma unroll
  for (int kk = 0; kk < 8; ++kk) {
    bf16x8 af[4], bh[4];
#pragma unroll
    for (int mf = 0; mf < 4; ++mf) {
      const int row = mf * 16 + l16;
      af[mf] = *(const bf16x8*)((const char*)As + row * 512 +
                                ((kk * 64 + lg16 * 16) ^ ((row & 7) << 4)));
    }
#pragma unroll
    for (int nf = 0; nf < 4; ++nf) {
      const int col = w * 64 + nf * 16 + l16;
      bh[nf] = *(const bf16x8*)(Wt + (size_t)col * 256 + kk * 32 + lg16 * 8);
    }
#pragma unroll
    for (int mf = 0; mf < 4; ++mf)
#pragma unroll
      for (int nf = 0; nf < 4; ++nf)
        acc[mf][nf] = __builtin_amdgcn_mfma_f32_16x16x32_bf16(af[mf], bh[nf], acc[mf][nf], 0, 0, 0);
  }
#pragma unroll
  for (int mf = 0; mf < 4; ++mf) {
    const int rbase = mf * 16 + lg16 * 4;
    const uchar4 mk = *(const uchar4*)(mask + row0 + rbase);
#pragma unroll
    for (int nf = 0; nf < 4; ++nf) {
      const int col = w * 64 + nf * 16 + l16;
      const float bb = bias[col];
#pragma unroll
      for (int r = 0; r < 4; ++r) {
        const unsigned char m = (r == 0) ? mk.x : (r == 1) ? mk.y : (r == 2) ? mk.z : mk.w;
        const float v = m ? 0.f : (acc[mf][nf][r] + bb);
        V[(size_t)(row0 + rbase + r) * 256 + col] = __float2bfloat16(v);
      }
    }
  }
}

// ---------------- K2: q = qf+qp; [off|lg] = q @ Wcat -> bf16 ----------------
// (byte-identical to round 11 — proven)
__global__ __launch_bounds__(256) void k_offattn(const float* __restrict__ qf,
                                                 const float* __restrict__ qp,
                                                 const unsigned short* __restrict__ Wt,
                                                 const float* __restrict__ boff,
                                                 const float* __restrict__ battn,
                                                 bf16* __restrict__ off,
                                                 bf16* __restrict__ lg) {
  __shared__ unsigned short As[64 * 256];
  const int tid = threadIdx.x;
  const int lane = tid & 63, w = tid >> 6;
  const int row0 = blockIdx.x * 64;
#pragma unroll
  for (int it = 0; it < 8; ++it) {
    const int cid = it * 256 + tid;
    const int row = cid >> 5, c = cid & 31;
    const float4* pf = (const float4*)(qf + (size_t)(row0 + row) * 256 + c * 8);
    const float4* pp = (const float4*)(qp + (size_t)(row0 + row) * 256 + c * 8);
    const float4 a0 = pf[0], a1 = pf[1], b0 = pp[0], b1 = pp[1];
    union { unsigned short u[8]; uint4 q; } pk;
    pk.u[0] = f2bf(a0.x + b0.x); pk.u[1] = f2bf(a0.y + b0.y);
    pk.u[2] = f2bf(a0.z + b0.z); pk.u[3] = f2bf(a0.w + b0.w);
    pk.u[4] = f2bf(a1.x + b1.x); pk.u[5] = f2bf(a1.y + b1.y);
    pk.u[6] = f2bf(a1.z + b1.z); pk.u[7] = f2bf(a1.w + b1.w);
    *(uint4*)((char*)As + row * 512 + ((c * 16) ^ ((row & 7) << 4))) = pk.q;
  }
  __syncthreads();
  const int lg16 = lane >> 4, l16 = lane & 15;
  f32x4 acc[4][6] = {};
#pragma unroll
  for (int kk = 0; kk < 8; ++kk) {
    bf16x8 af[4], bh[6];
#pragma unroll
    for (int mf = 0; mf < 4; ++mf) {
      const int row = mf * 16 + l16;
      af[mf] = *(const bf16x8*)((const char*)As + row * 512 +
                                ((kk * 64 + lg16 * 16) ^ ((row & 7) << 4)));
    }
#pragma unroll
    for (int nf = 0; nf < 6; ++nf) {
      const int col = w * 96 + nf * 16 + l16;
      bh[nf] = *(const bf16x8*)(Wt + (size_t)col * 256 + kk * 32 + lg16 * 8);
    }
#pragma unroll
    for (int mf = 0; mf < 4; ++mf)
#pragma unroll
      for (int nf = 0; nf < 6; ++nf)
        acc[mf][nf] = __builtin_amdgcn_mfma_f32_16x16x32_bf16(af[mf], bh[nf], acc[mf][nf], 0, 0, 0);
  }
#pragma unroll
  for (int mf = 0; mf < 4; ++mf) {
    const int rbase = row0 + mf * 16 + lg16 * 4;
#pragma unroll
    for (int nf = 0; nf < 6; ++nf) {
      const int col = w * 96 + nf * 16 + l16;
      if (col < 256) {
        const float bb = boff[col];
#pragma unroll
        for (int r = 0; r < 4; ++r)
          off[(size_t)(rbase + r) * 256 + col] = __float2bfloat16(acc[mf][nf][r] + bb);
      } else {
        const float bb = battn[col - 256];
#pragma unroll
        for (int r = 0; r < 4; ++r)
          lg[(size_t)(rbase + r) * 128 + (col - 256)] = __float2bfloat16(acc[mf][nf][r] + bb);
      }
    }
  }
}

// ---------------- K3: softmax + bilinear gather + attn-weighted sum ---------
// Output now bf16 `samp`, ALIASED onto `off` (safe: each block's off/lg reads
// are row-local and complete at the phase1->2 barrier; V gather untouched).
// d_out is NOT touched by this kernel anymore.
__global__ __launch_bounds__(256) void k_sample(const bf16* __restrict__ V,
                                                const bf16* off,
                                                const bf16* __restrict__ lg,
                                                const float* __restrict__ qpts,
                                                const float* __restrict__ vratio,
                                                unsigned short* samp) {
  __shared__ uint2 sIdx[QB * 16 * 9];  // [q][i][h(pad 9)] 4x u16 token idx
  __shared__ uint2 sW[QB * 16 * 9];    // 4x bf16 premultiplied weights
  __shared__ float sMax[QB * 8], sInv[QB * 8];
  const int t = threadIdx.x;
  const int row0 = blockIdx.x * QB;

  if (t < QB * 8) {
    const int q = t >> 3, h = t & 7;
    const int row = row0 + q;
    const uint4* lp = (const uint4*)(lg + (size_t)row * 128 + h * 16);
    uint4 u0 = lp[0], u1 = lp[1];
    float v[16];
    v[0] = bflo(u0.x); v[1] = bfhi(u0.x); v[2] = bflo(u0.y); v[3] = bfhi(u0.y);
    v[4] = bflo(u0.z); v[5] = bfhi(u0.z); v[6] = bflo(u0.w); v[7] = bfhi(u0.w);
    v[8] = bflo(u1.x); v[9] = bfhi(u1.x); v[10] = bflo(u1.y); v[11] = bfhi(u1.y);
    v[12] = bflo(u1.z); v[13] = bfhi(u1.z); v[14] = bflo(u1.w); v[15] = bfhi(u1.w);
    float m = v[0];
#pragma unroll
    for (int i = 1; i < 16; ++i) m = fmaxf(m, v[i]);
    float s = 0.f;
#pragma unroll
    for (int i = 0; i < 16; ++i) s += __expf(v[i] - m);
    sMax[t] = m;
    sInv[t] = 1.f / s;
  }
  __syncthreads();

  const int Wl_[4] = {128, 64, 32, 16};
  const int st_[4] = {0, 16384, 20480, 21504};
#pragma unroll
  for (int tt = 0; tt < 4; ++tt) {
    const int sid = t + tt * 256;
    const int q = sid >> 7, s = sid & 127;
    const int h = s >> 4, i = s & 15, l = i >> 2;
    const int row = row0 + q;
    const int b = row >= SEQ;  // NB == 2
    const unsigned int u = *(const unsigned int*)(off + (size_t)row * 256 + s * 2);
    const float ox = bflo(u), oy = bfhi(u);
    const float lgv = bf2f(*(const unsigned short*)(lg + (size_t)row * 128 + s));
    const float e = __expf(lgv - sMax[q * 8 + h]) * sInv[q * 8 + h];
    const float px = qpts[(size_t)row * 2], py = qpts[(size_t)row * 2 + 1];
    const float vrx = vratio[b * 8 + l * 2], vry = vratio[b * 8 + l * 2 + 1];
    const int Wl = Wl_[l];
    const float fW = (float)Wl;
    const float x = fmaf(px * vrx, fW, ox) - 0.5f;
    const float y = fmaf(py * vry, fW, oy) - 0.5f;
    const float fx = floorf(x), fy = floorf(y);
    const float wx = x - fx, wy = y - fy;
    const int x0 = (int)fx, y0 = (int)fy;
    const int x1 = x0 + 1, y1 = y0 + 1;
    const int xc0 = min(max(x0, 0), Wl - 1), xc1 = min(max(x1, 0), Wl - 1);
    const int yc0 = min(max(y0, 0), Wl - 1), yc1 = min(max(y1, 0), Wl - 1);
    const float ox0 = (x0 >= 0 && x0 < Wl) ? e : 0.f;   // fold attn weight in
    const float ox1 = (x1 >= 0 && x1 < Wl) ? e : 0.f;
    const float oy0 = (y0 >= 0 && y0 < Wl) ? 1.f : 0.f;
    const float oy1 = (y1 >= 0 && y1 < Wl) ? 1.f : 0.f;
    const int base = b * SEQ + st_[l];   // max token idx 43519 < 65536 -> u16 ok
    const int r0 = base + yc0 * Wl, r1 = base + yc1 * Wl;
    uint2 I, Wp;
    I.x = (unsigned int)(r0 + xc0) | ((unsigned int)(r0 + xc1) << 16);
    I.y = (unsigned int)(r1 + xc0) | ((unsigned int)(r1 + xc1) << 16);
    Wp.x = (unsigned int)f2bf((1.f - wx) * (1.f - wy) * ox0 * oy0) |
           ((unsigned int)f2bf(wx * (1.f - wy) * ox1 * oy0) << 16);
    Wp.y = (unsigned int)f2bf((1.f - wx) * wy * ox0 * oy1) |
           ((unsigned int)f2bf(wx * wy * ox1 * oy1) << 16);
    sIdx[(q * 16 + i) * 9 + h] = I;
    sW[(q * 16 + i) * 9 + h] = Wp;
  }
  __syncthreads();  // all off/lg reads for this block's rows complete here

  const int q = t >> 5, sub = t & 31;
  const int h = sub >> 2, dg = sub & 3;
  const int row = row0 + q;
  const bf16* vb = V + h * 32 + dg * 8;
  float a0 = 0.f, a1 = 0.f, a2 = 0.f, a3 = 0.f;
  float a4 = 0.f, a5 = 0.f, a6 = 0.f, a7 = 0.f;
#pragma unroll
  for (int i = 0; i < 16; ++i) {
    const uint2 I = sIdx[(q * 16 + i) * 9 + h];
    const uint2 Wp = sW[(q * 16 + i) * 9 + h];
    const int i0 = I.x & 0xffff, i1 = I.x >> 16;
    const int i2 = I.y & 0xffff, i3 = I.y >> 16;
    const float w0 = bflo(Wp.x), w1 = bfhi(Wp.x);
    const float w2 = bflo(Wp.y), w3 = bfhi(Wp.y);
    {
      const uint4 u = *(const uint4*)(vb + (size_t)i0 * 256);
      a0 = fmaf(w0, bflo(u.x), a0); a1 = fmaf(w0, bfhi(u.x), a1);
      a2 = fmaf(w0, bflo(u.y), a2); a3 = fmaf(w0, bfhi(u.y), a3);
      a4 = fmaf(w0, bflo(u.z), a4); a5 = fmaf(w0, bfhi(u.z), a5);
      a6 = fmaf(w0, bflo(u.w), a6); a7 = fmaf(w0, bfhi(u.w), a7);
    }
    {
      const uint4 u = *(const uint4*)(vb + (size_t)i1 * 256);
      a0 = fmaf(w1, bflo(u.x), a0); a1 = fmaf(w1, bfhi(u.x), a1);
      a2 = fmaf(w1, bflo(u.y), a2); a3 = fmaf(w1, bfhi(u.y), a3);
      a4 = fmaf(w1, bflo(u.z), a4); a5 = fmaf(w1, bfhi(u.z), a5);
      a6 = fmaf(w1, bflo(u.w), a6); a7 = fmaf(w1, bfhi(u.w), a7);
    }
    {
      const uint4 u = *(const uint4*)(vb + (size_t)i2 * 256);
      a0 = fmaf(w2, bflo(u.x), a0); a1 = fmaf(w2, bfhi(u.x), a1);
      a2 = fmaf(w2, bflo(u.y), a2); a3 = fmaf(w2, bfhi(u.y), a3);
      a4 = fmaf(w2, bflo(u.z), a4); a5 = fmaf(w2, bfhi(u.z), a5);
      a6 = fmaf(w2, bflo(u.w), a6); a7 = fmaf(w2, bfhi(u.w), a7);
    }
    {
      const uint4 u = *(const uint4*)(vb + (size_t)i3 * 256);
      a0 = fmaf(w3, bflo(u.x), a0); a1 = fmaf(w3, bfhi(u.x), a1);
      a2 = fmaf(w3, bflo(u.y), a2); a3 = fmaf(w3, bfhi(u.y), a3);
      a4 = fmaf(w3, bflo(u.z), a4); a5 = fmaf(w3, bfhi(u.z), a5);
      a6 = fmaf(w3, bflo(u.w), a6); a7 = fmaf(w3, bfhi(u.w), a7);
    }
  }
  uint4 pk;
  pk.x = (unsigned int)f2bf(a0) | ((unsigned int)f2bf(a1) << 16);
  pk.y = (unsigned int)f2bf(a2) | ((unsigned int)f2bf(a3) << 16);
  pk.z = (unsigned int)f2bf(a4) | ((unsigned int)f2bf(a5) << 16);
  pk.w = (unsigned int)f2bf(a6) | ((unsigned int)f2bf(a7) << 16);
  *(uint4*)((char*)samp + (size_t)row * 512 + (h * 32 + dg * 8) * 2) = pk;
}

// ---------------- K4: upd = samp @ WoutT + bout -> bf16 ---------------------
// k_value clone with bf16 A-input: staging is a straight uint4 copy (samp is
// already bf16). MFMA body + store epilogue structurally identical to proven.
__global__ __launch_bounds__(256) void k_upd(const unsigned short* __restrict__ A,
                                             const unsigned short* __restrict__ Wt,
                                             const float* __restrict__ bias,
                                             bf16* __restrict__ U) {
  __shared__ unsigned short As[64 * 256];  // 32KB, XOR-swizzled
  const int tid = threadIdx.x;
  const int lane = tid & 63, w = tid >> 6;
  const int row0 = blockIdx.x * 64;
#pragma unroll
  for (int it = 0; it < 8; ++it) {
    const int cid = it * 256 + tid;
    const int row = cid >> 5, c = cid & 31;
    const uint4 q = *(const uint4*)(A + (size_t)(row0 + row) * 256 + c * 8);
    *(uint4*)((char*)As + row * 512 + ((c * 16) ^ ((row & 7) << 4))) = q;
  }
  __syncthreads();
  const int lg16 = lane >> 4, l16 = lane & 15;
  f32x4 acc[4][4] = {};
#pragma unroll
  for (int kk = 0; kk < 8; ++kk) {
    bf16x8 af[4], bh[4];
#pragma unroll
    for (int mf = 0; mf < 4; ++mf) {
      const int row = mf * 16 + l16;
      af[mf] = *(const bf16x8*)((const char*)As + row * 512 +
                                ((kk * 64 + lg16 * 16) ^ ((row & 7) << 4)));
    }
#pragma unroll
    for (int nf = 0; nf < 4; ++nf) {
      const int col = w * 64 + nf * 16 + l16;
      bh[nf] = *(const bf16x8*)(Wt + (size_t)col * 256 + kk * 32 + lg16 * 8);
    }
#pragma unroll
    for (int mf = 0; mf < 4; ++mf)
#pragma unroll
      for (int nf = 0; nf < 4; ++nf)
        acc[mf][nf] = __builtin_amdgcn_mfma_f32_16x16x32_bf16(af[mf], bh[nf], acc[mf][nf], 0, 0, 0);
  }
#pragma unroll
  for (int mf = 0; mf < 4; ++mf) {
    const int rbase = row0 + mf * 16 + lg16 * 4;
#pragma unroll
    for (int nf = 0; nf < 4; ++nf) {
      const int col = w * 64 + nf * 16 + l16;
      const float bb = bias[col];
#pragma unroll
      for (int r = 0; r < 4; ++r)
        U[(size_t)(rbase + r) * 256 + col] = __float2bfloat16(acc[mf][nf][r] + bb);
    }
  }
}

// ---------------- K5: y = LN(qf + upd) — SOLE writer of d_out ---------------
__global__ __launch_bounds__(256) void k_ln(const unsigned short* __restrict__ upd,
                                            const float* __restrict__ qf,
                                            const float* __restrict__ gamma,
                                            const float* __restrict__ beta,
                                            float* __restrict__ y) {
  const int w = threadIdx.x >> 6, lane = threadIdx.x & 63;
  const int row = blockIdx.x * 4 + w;
  const int c = lane * 4;
  const ushort4 u = *(const ushort4*)(upd + (size_t)row * 256 + c);
  const float4 qv = *(const float4*)(qf + (size_t)row * 256 + c);
  const float x0 = qv.x + bf2f(u.x);
  const float x1 = qv.y + bf2f(u.y);
  const float x2 = qv.z + bf2f(u.z);
  const float x3 = qv.w + bf2f(u.w);
  float s1 = x0 + x1 + x2 + x3;
  float s2 = x0 * x0 + x1 * x1 + x2 * x2 + x3 * x3;
#pragma unroll
  for (int o = 32; o >= 1; o >>= 1) {
    s1 += __shfl_xor(s1, o);
    s2 += __shfl_xor(s2, o);
  }
  const float mu = s1 * (1.f / 256.f);
  const float var = s2 * (1.f / 256.f) - mu * mu;
  const float rsig = rsqrtf(var + LN_EPS);
  const float4 g = *(const float4*)(gamma + c);
  const float4 bt = *(const float4*)(beta + c);
  float4 o;
  o.x = (x0 - mu) * rsig * g.x + bt.x;
  o.y = (x1 - mu) * rsig * g.y + bt.y;
  o.z = (x2 - mu) * rsig * g.z + bt.z;
  o.w = (x3 - mu) * rsig * g.w + bt.w;
  *(float4*)(y + (size_t)row * 256 + c) = o;
}

extern "C" void kernel_launch(void* const* d_in, const int* in_sizes, int n_in,
                              void* d_out, int out_size, void* d_ws, size_t ws_size,
                              hipStream_t stream) {
  const float* img_feat = (const float*)d_in[0];
  const unsigned char* img_mask = (const unsigned char*)d_in[2];
  const float* vratio = (const float*)d_in[3];
  const float* qf = (const float*)d_in[4];
  const float* qp = (const float*)d_in[5];
  const float* qpts = (const float*)d_in[6];
  const float* Wv = (const float*)d_in[7];
  const float* bv = (const float*)d_in[8];
  const float* Woff = (const float*)d_in[9];
  const float* boff = (const float*)d_in[10];
  const float* Wattn = (const float*)d_in[11];
  const float* battn = (const float*)d_in[12];
  const float* Wout = (const float*)d_in[13];
  const float* bout = (const float*)d_in[14];
  const float* gamma = (const float*)d_in[15];
  const float* beta = (const float*)d_in[16];

  char* ws = (char*)d_ws;
  bf16* V = (bf16*)ws;                                   // 22.3 MB (reused as upd)
  bf16* off = (bf16*)(ws + (size_t)NROW * 256 * 2);      // 22.3 MB (reused as samp)
  bf16* lg = (bf16*)(ws + (size_t)NROW * 256 * 4);       // 11.1 MB
  unsigned short* wbase =
      (unsigned short*)(ws + (size_t)NROW * 256 * 4 + (size_t)NROW * 128 * 2);
  unsigned short* WvT = wbase;              // 65536 shorts
  unsigned short* WcatT = WvT + 65536;      // 98304 shorts
  unsigned short* WoutT = WcatT + 98304;    // 65536 shorts -> ends 56.16MB (< proven 56.36MB)

  dim3 blk(256);
  k_trans<<<256, blk, 0, stream>>>(Wv, WvT, 256);
  k_trans<<<256, blk, 0, stream>>>(Woff, WcatT, 256);
  k_trans<<<128, blk, 0, stream>>>(Wattn, WcatT + 256 * 256, 128);
  k_trans<<<256, blk, 0, stream>>>(Wout, WoutT, 256);
  k_value<<<NROW / 64, blk, 0, stream>>>(img_feat, WvT, bv, img_mask, V);
  k_offattn<<<NROW / 64, blk, 0, stream>>>(qf, qp, WcatT, boff, battn, off, lg);
  k_sample<<<NROW / QB, blk, 0, stream>>>(V, off, lg, qpts, vratio,
                                          (unsigned short*)off /* samp alias */);
  k_upd<<<NROW / 64, blk, 0, stream>>>((const unsigned short*)off /* samp */, WoutT,
                                       bout, V /* = upd, dead */);
  k_ln<<<NROW / 4, blk, 0, stream>>>((const unsigned short*)V, qf, gamma, beta,
                                     (float*)d_out);
}

// Round 16
// 214.106 us; speedup vs baseline: 2.7062x; 1.0181x over previous
//
#include <hip/hip_runtime.h>
#include <hip/hip_bf16.h>

#define EMB 256
#define SEQ 21760
#define NB 2
#define NROW (NB * SEQ)   // 43520
#define QB 8              // queries per k_sample block
#define LN_EPS 1e-5f

typedef __hip_bfloat16 bf16;
typedef short bf16x8 __attribute__((ext_vector_type(8)));
typedef float f32x4 __attribute__((ext_vector_type(4)));

__device__ __forceinline__ unsigned short f2bf(float f) {
  __hip_bfloat16 h = __float2bfloat16(f);
  return *reinterpret_cast<unsigned short*>(&h);
}
__device__ __forceinline__ float bf2f(unsigned short u) {
  return __uint_as_float((unsigned int)u << 16);
}
__device__ __forceinline__ float bflo(unsigned int u) { return __uint_as_float(u << 16); }
__device__ __forceinline__ float bfhi(unsigned int u) { return __uint_as_float(u & 0xffff0000u); }

// ---------------- K0: bf16 transpose of W[k][n] -> Wt[n][k] -----------------
__global__ __launch_bounds__(256) void k_trans(const float* __restrict__ src,
                                               unsigned short* __restrict__ dst, int N) {
  const int n = blockIdx.x, k = threadIdx.x;
  dst[n * 256 + k] = f2bf(src[k * N + n]);
}

// ---------------- K1: V = mask ? 0 : (A @ Wt + bias)  -> bf16 HEAD-MAJOR ----
// Same proven staging/MFMA body; store is now V[h][token][32ch] so the
// gather's bilinear x-pair lands in one 128B cache line.
__global__ __launch_bounds__(256) void k_value(const float* __restrict__ A,
                                               const unsigned short* __restrict__ Wt,
                                               const float* __restrict__ bias,
                                               const unsigned char* __restrict__ mask,
                                               bf16* __restrict__ V) {
  __shared__ unsigned short As[64 * 256];  // 32KB, XOR-swizzled
  const int tid = threadIdx.x;
  const int lane = tid & 63, w = tid >> 6;
  const int row0 = blockIdx.x * 64;
#pragma unroll
  for (int it = 0; it < 8; ++it) {
    const int cid = it * 256 + tid;
    const int row = cid >> 5, c = cid & 31;
    const float4* p = (const float4*)(A + (size_t)(row0 + row) * 256 + c * 8);
    const float4 a0 = p[0], a1 = p[1];
    union { unsigned short u[8]; uint4 q; } pk;
    pk.u[0] = f2bf(a0.x); pk.u[1] = f2bf(a0.y); pk.u[2] = f2bf(a0.z); pk.u[3] = f2bf(a0.w);
    pk.u[4] = f2bf(a1.x); pk.u[5] = f2bf(a1.y); pk.u[6] = f2bf(a1.z); pk.u[7] = f2bf(a1.w);
    *(uint4*)((char*)As + row * 512 + ((c * 16) ^ ((row & 7) << 4))) = pk.q;
  }
  __syncthreads();
  const int lg16 = lane >> 4, l16 = lane & 15;
  f32x4 acc[4][4] = {};
#pragma unroll
  for (int kk = 0; kk < 8; ++kk) {
    bf16x8 af[4], bh[4];
#pragma unroll
    for (int mf = 0; mf < 4; ++mf) {
      const int row = mf * 16 + l16;
      af[mf] = *(const bf16x8*)((const char*)As + row * 512 +
                                ((kk * 64 + lg16 * 16) ^ ((row & 7) << 4)));
    }
#pragma unroll
    for (int nf = 0; nf < 4; ++nf) {
      const int col = w * 64 + nf * 16 + l16;
      bh[nf] = *(const bf16x8*)(Wt + (size_t)col * 256 + kk * 32 + lg16 * 8);
    }
#pragma unroll
    for (int mf = 0; mf < 4; ++mf)
#pragma unroll
      for (int nf = 0; nf < 4; ++nf)
        acc[mf][nf] = __builtin_amdgcn_mfma_f32_16x16x32_bf16(af[mf], bh[nf], acc[mf][nf], 0, 0, 0);
  }
#pragma unroll
  for (int mf = 0; mf < 4; ++mf) {
    const int rbase = mf * 16 + lg16 * 4;
    const uchar4 mk = *(const uchar4*)(mask + row0 + rbase);
#pragma unroll
    for (int nf = 0; nf < 4; ++nf) {
      const int col = w * 64 + nf * 16 + l16;
      const int hh = col >> 5, ch = col & 31;   // head-major decomposition
      const float bb = bias[col];
#pragma unroll
      for (int r = 0; r < 4; ++r) {
        const unsigned char m = (r == 0) ? mk.x : (r == 1) ? mk.y : (r == 2) ? mk.z : mk.w;
        const float v = m ? 0.f : (acc[mf][nf][r] + bb);
        V[(size_t)hh * (NROW * 32) + (size_t)(row0 + rbase + r) * 32 + ch] =
            __float2bfloat16(v);
      }
    }
  }
}

// ---------------- K2: q = qf+qp; [off|lg] = q @ Wcat -> bf16 ----------------
// (byte-identical to round 11 — proven)
__global__ __launch_bounds__(256) void k_offattn(const float* __restrict__ qf,
                                                 const float* __restrict__ qp,
                                                 const unsigned short* __restrict__ Wt,
                                                 const float* __restrict__ boff,
                                                 const float* __restrict__ battn,
                                                 bf16* __restrict__ off,
                                                 bf16* __restrict__ lg) {
  __shared__ unsigned short As[64 * 256];
  const int tid = threadIdx.x;
  const int lane = tid & 63, w = tid >> 6;
  const int row0 = blockIdx.x * 64;
#pragma unroll
  for (int it = 0; it < 8; ++it) {
    const int cid = it * 256 + tid;
    const int row = cid >> 5, c = cid & 31;
    const float4* pf = (const float4*)(qf + (size_t)(row0 + row) * 256 + c * 8);
    const float4* pp = (const float4*)(qp + (size_t)(row0 + row) * 256 + c * 8);
    const float4 a0 = pf[0], a1 = pf[1], b0 = pp[0], b1 = pp[1];
    union { unsigned short u[8]; uint4 q; } pk;
    pk.u[0] = f2bf(a0.x + b0.x); pk.u[1] = f2bf(a0.y + b0.y);
    pk.u[2] = f2bf(a0.z + b0.z); pk.u[3] = f2bf(a0.w + b0.w);
    pk.u[4] = f2bf(a1.x + b1.x); pk.u[5] = f2bf(a1.y + b1.y);
    pk.u[6] = f2bf(a1.z + b1.z); pk.u[7] = f2bf(a1.w + b1.w);
    *(uint4*)((char*)As + row * 512 + ((c * 16) ^ ((row & 7) << 4))) = pk.q;
  }
  __syncthreads();
  const int lg16 = lane >> 4, l16 = lane & 15;
  f32x4 acc[4][6] = {};
#pragma unroll
  for (int kk = 0; kk < 8; ++kk) {
    bf16x8 af[4], bh[6];
#pragma unroll
    for (int mf = 0; mf < 4; ++mf) {
      const int row = mf * 16 + l16;
      af[mf] = *(const bf16x8*)((const char*)As + row * 512 +
                                ((kk * 64 + lg16 * 16) ^ ((row & 7) << 4)));
    }
#pragma unroll
    for (int nf = 0; nf < 6; ++nf) {
      const int col = w * 96 + nf * 16 + l16;
      bh[nf] = *(const bf16x8*)(Wt + (size_t)col * 256 + kk * 32 + lg16 * 8);
    }
#pragma unroll
    for (int mf = 0; mf < 4; ++mf)
#pragma unroll
      for (int nf = 0; nf < 6; ++nf)
        acc[mf][nf] = __builtin_amdgcn_mfma_f32_16x16x32_bf16(af[mf], bh[nf], acc[mf][nf], 0, 0, 0);
  }
#pragma unroll
  for (int mf = 0; mf < 4; ++mf) {
    const int rbase = row0 + mf * 16 + lg16 * 4;
#pragma unroll
    for (int nf = 0; nf < 6; ++nf) {
      const int col = w * 96 + nf * 16 + l16;
      if (col < 256) {
        const float bb = boff[col];
#pragma unroll
        for (int r = 0; r < 4; ++r)
          off[(size_t)(rbase + r) * 256 + col] = __float2bfloat16(acc[mf][nf][r] + bb);
      } else {
        const float bb = battn[col - 256];
#pragma unroll
        for (int r = 0; r < 4; ++r)
          lg[(size_t)(rbase + r) * 128 + (col - 256)] = __float2bfloat16(acc[mf][nf][r] + bb);
      }
    }
  }
}

// ---------------- K3: softmax + bilinear gather + attn-weighted sum ---------
// V is head-major [h][token][32ch]. samp (bf16) aliases off. No d_out use.
__global__ __launch_bounds__(256) void k_sample(const bf16* __restrict__ V,
                                                const bf16* off,
                                                const bf16* __restrict__ lg,
                                                const float* __restrict__ qpts,
                                                const float* __restrict__ vratio,
                                                unsigned short* samp) {
  __shared__ uint2 sIdx[QB * 16 * 9];  // [q][i][h(pad 9)] 4x u16 token idx
  __shared__ uint2 sW[QB * 16 * 9];    // 4x bf16 premultiplied weights
  __shared__ float sMax[QB * 8], sInv[QB * 8];
  const int t = threadIdx.x;
  const int row0 = blockIdx.x * QB;

  if (t < QB * 8) {
    const int q = t >> 3, h = t & 7;
    const int row = row0 + q;
    const uint4* lp = (const uint4*)(lg + (size_t)row * 128 + h * 16);
    uint4 u0 = lp[0], u1 = lp[1];
    float v[16];
    v[0] = bflo(u0.x); v[1] = bfhi(u0.x); v[2] = bflo(u0.y); v[3] = bfhi(u0.y);
    v[4] = bflo(u0.z); v[5] = bfhi(u0.z); v[6] = bflo(u0.w); v[7] = bfhi(u0.w);
    v[8] = bflo(u1.x); v[9] = bfhi(u1.x); v[10] = bflo(u1.y); v[11] = bfhi(u1.y);
    v[12] = bflo(u1.z); v[13] = bfhi(u1.z); v[14] = bflo(u1.w); v[15] = bfhi(u1.w);
    float m = v[0];
#pragma unroll
    for (int i = 1; i < 16; ++i) m = fmaxf(m, v[i]);
    float s = 0.f;
#pragma unroll
    for (int i = 0; i < 16; ++i) s += __expf(v[i] - m);
    sMax[t] = m;
    sInv[t] = 1.f / s;
  }
  __syncthreads();

  const int Wl_[4] = {128, 64, 32, 16};
  const int st_[4] = {0, 16384, 20480, 21504};
#pragma unroll
  for (int tt = 0; tt < 4; ++tt) {
    const int sid = t + tt * 256;
    const int q = sid >> 7, s = sid & 127;
    const int h = s >> 4, i = s & 15, l = i >> 2;
    const int row = row0 + q;
    const int b = row >= SEQ;  // NB == 2
    const unsigned int u = *(const unsigned int*)(off + (size_t)row * 256 + s * 2);
    const float ox = bflo(u), oy = bfhi(u);
    const float lgv = bf2f(*(const unsigned short*)(lg + (size_t)row * 128 + s));
    const float e = __expf(lgv - sMax[q * 8 + h]) * sInv[q * 8 + h];
    const float px = qpts[(size_t)row * 2], py = qpts[(size_t)row * 2 + 1];
    const float vrx = vratio[b * 8 + l * 2], vry = vratio[b * 8 + l * 2 + 1];
    const int Wl = Wl_[l];
    const float fW = (float)Wl;
    const float x = fmaf(px * vrx, fW, ox) - 0.5f;
    const float y = fmaf(py * vry, fW, oy) - 0.5f;
    const float fx = floorf(x), fy = floorf(y);
    const float wx = x - fx, wy = y - fy;
    const int x0 = (int)fx, y0 = (int)fy;
    const int x1 = x0 + 1, y1 = y0 + 1;
    const int xc0 = min(max(x0, 0), Wl - 1), xc1 = min(max(x1, 0), Wl - 1);
    const int yc0 = min(max(y0, 0), Wl - 1), yc1 = min(max(y1, 0), Wl - 1);
    const float ox0 = (x0 >= 0 && x0 < Wl) ? e : 0.f;   // fold attn weight in
    const float ox1 = (x1 >= 0 && x1 < Wl) ? e : 0.f;
    const float oy0 = (y0 >= 0 && y0 < Wl) ? 1.f : 0.f;
    const float oy1 = (y1 >= 0 && y1 < Wl) ? 1.f : 0.f;
    const int base = b * SEQ + st_[l];   // max token idx 43519 < 65536 -> u16 ok
    const int r0 = base + yc0 * Wl, r1 = base + yc1 * Wl;
    uint2 I, Wp;
    I.x = (unsigned int)(r0 + xc0) | ((unsigned int)(r0 + xc1) << 16);
    I.y = (unsigned int)(r1 + xc0) | ((unsigned int)(r1 + xc1) << 16);
    Wp.x = (unsigned int)f2bf((1.f - wx) * (1.f - wy) * ox0 * oy0) |
           ((unsigned int)f2bf(wx * (1.f - wy) * ox1 * oy0) << 16);
    Wp.y = (unsigned int)f2bf((1.f - wx) * wy * ox0 * oy1) |
           ((unsigned int)f2bf(wx * wy * ox1 * oy1) << 16);
    sIdx[(q * 16 + i) * 9 + h] = I;
    sW[(q * 16 + i) * 9 + h] = Wp;
  }
  __syncthreads();  // all off/lg reads for this block's rows complete here

  const int q = t >> 5, sub = t & 31;
  const int h = sub >> 2, dg = sub & 3;
  const int row = row0 + q;
  const bf16* vb = V + (size_t)h * (NROW * 32) + dg * 8;  // head-major base
  float a0 = 0.f, a1 = 0.f, a2 = 0.f, a3 = 0.f;
  float a4 = 0.f, a5 = 0.f, a6 = 0.f, a7 = 0.f;
#pragma unroll
  for (int i = 0; i < 16; ++i) {
    const uint2 I = sIdx[(q * 16 + i) * 9 + h];
    const uint2 Wp = sW[(q * 16 + i) * 9 + h];
    const int i0 = I.x & 0xffff, i1 = I.x >> 16;
    const int i2 = I.y & 0xffff, i3 = I.y >> 16;
    const float w0 = bflo(Wp.x), w1 = bfhi(Wp.x);
    const float w2 = bflo(Wp.y), w3 = bfhi(Wp.y);
    {
      const uint4 u = *(const uint4*)(vb + (size_t)i0 * 32);
      a0 = fmaf(w0, bflo(u.x), a0); a1 = fmaf(w0, bfhi(u.x), a1);
      a2 = fmaf(w0, bflo(u.y), a2); a3 = fmaf(w0, bfhi(u.y), a3);
      a4 = fmaf(w0, bflo(u.z), a4); a5 = fmaf(w0, bfhi(u.z), a5);
      a6 = fmaf(w0, bflo(u.w), a6); a7 = fmaf(w0, bfhi(u.w), a7);
    }
    {
      const uint4 u = *(const uint4*)(vb + (size_t)i1 * 32);
      a0 = fmaf(w1, bflo(u.x), a0); a1 = fmaf(w1, bfhi(u.x), a1);
      a2 = fmaf(w1, bflo(u.y), a2); a3 = fmaf(w1, bfhi(u.y), a3);
      a4 = fmaf(w1, bflo(u.z), a4); a5 = fmaf(w1, bfhi(u.z), a5);
      a6 = fmaf(w1, bflo(u.w), a6); a7 = fmaf(w1, bfhi(u.w), a7);
    }
    {
      const uint4 u = *(const uint4*)(vb + (size_t)i2 * 32);
      a0 = fmaf(w2, bflo(u.x), a0); a1 = fmaf(w2, bfhi(u.x), a1);
      a2 = fmaf(w2, bflo(u.y), a2); a3 = fmaf(w2, bfhi(u.y), a3);
      a4 = fmaf(w2, bflo(u.z), a4); a5 = fmaf(w2, bfhi(u.z), a5);
      a6 = fmaf(w2, bflo(u.w), a6); a7 = fmaf(w2, bfhi(u.w), a7);
    }
    {
      const uint4 u = *(const uint4*)(vb + (size_t)i3 * 32);
      a0 = fmaf(w3, bflo(u.x), a0); a1 = fmaf(w3, bfhi(u.x), a1);
      a2 = fmaf(w3, bflo(u.y), a2); a3 = fmaf(w3, bfhi(u.y), a3);
      a4 = fmaf(w3, bflo(u.z), a4); a5 = fmaf(w3, bfhi(u.z), a5);
      a6 = fmaf(w3, bflo(u.w), a6); a7 = fmaf(w3, bfhi(u.w), a7);
    }
  }
  uint4 pk;
  pk.x = (unsigned int)f2bf(a0) | ((unsigned int)f2bf(a1) << 16);
  pk.y = (unsigned int)f2bf(a2) | ((unsigned int)f2bf(a3) << 16);
  pk.z = (unsigned int)f2bf(a4) | ((unsigned int)f2bf(a5) << 16);
  pk.w = (unsigned int)f2bf(a6) | ((unsigned int)f2bf(a7) << 16);
  *(uint4*)((char*)samp + (size_t)row * 512 + (h * 32 + dg * 8) * 2) = pk;
}

// ---------------- K4: upd = samp @ WoutT + bout -> bf16 ---------------------
// (byte-identical to round 15 — proven)
__global__ __launch_bounds__(256) void k_upd(const unsigned short* __restrict__ A,
                                             const unsigned short* __restrict__ Wt,
                                             const float* __restrict__ bias,
                                             bf16* __restrict__ U) {
  __shared__ unsigned short As[64 * 256];  // 32KB, XOR-swizzled
  const int tid = threadIdx.x;
  const int lane = tid & 63, w = tid >> 6;
  const int row0 = blockIdx.x * 64;
#pragma unroll
  for (int it = 0; it < 8; ++it) {
    const int cid = it * 256 + tid;
    const int row = cid >> 5, c = cid & 31;
    const uint4 q = *(const uint4*)(A + (size_t)(row0 + row) * 256 + c * 8);
    *(uint4*)((char*)As + row * 512 + ((c * 16) ^ ((row & 7) << 4))) = q;
  }
  __syncthreads();
  const int lg16 = lane >> 4, l16 = lane & 15;
  f32x4 acc[4][4] = {};
#pragma unroll
  for (int kk = 0; kk < 8; ++kk) {
    bf16x8 af[4], bh[4];
#pragma unroll
    for (int mf = 0; mf < 4; ++mf) {
      const int row = mf * 16 + l16;
      af[mf] = *(const bf16x8*)((const char*)As + row * 512 +
                                ((kk * 64 + lg16 * 16) ^ ((row & 7) << 4)));
    }
#pragma unroll
    for (int nf = 0; nf < 4; ++nf) {
      const int col = w * 64 + nf * 16 + l16;
      bh[nf] = *(const bf16x8*)(Wt + (size_t)col * 256 + kk * 32 + lg16 * 8);
    }
#pragma unroll
    for (int mf = 0; mf < 4; ++mf)
#pragma unroll
      for (int nf = 0; nf < 4; ++nf)
        acc[mf][nf] = __builtin_amdgcn_mfma_f32_16x16x32_bf16(af[mf], bh[nf], acc[mf][nf], 0, 0, 0);
  }
#pragma unroll
  for (int mf = 0; mf < 4; ++mf) {
    const int rbase = row0 + mf * 16 + lg16 * 4;
#pragma unroll
    for (int nf = 0; nf < 4; ++nf) {
      const int col = w * 64 + nf * 16 + l16;
      const float bb = bias[col];
#pragma unroll
      for (int r = 0; r < 4; ++r)
        U[(size_t)(rbase + r) * 256 + col] = __float2bfloat16(acc[mf][nf][r] + bb);
    }
  }
}

// ---------------- K5: y = LN(qf + upd) — SOLE writer of d_out ---------------
__global__ __launch_bounds__(256) void k_ln(const unsigned short* __restrict__ upd,
                                            const float* __restrict__ qf,
                                            const float* __restrict__ gamma,
                                            const float* __restrict__ beta,
                                            float* __restrict__ y) {
  const int w = threadIdx.x >> 6, lane = threadIdx.x & 63;
  const int row = blockIdx.x * 4 + w;
  const int c = lane * 4;
  const ushort4 u = *(const ushort4*)(upd + (size_t)row * 256 + c);
  const float4 qv = *(const float4*)(qf + (size_t)row * 256 + c);
  const float x0 = qv.x + bf2f(u.x);
  const float x1 = qv.y + bf2f(u.y);
  const float x2 = qv.z + bf2f(u.z);
  const float x3 = qv.w + bf2f(u.w);
  float s1 = x0 + x1 + x2 + x3;
  float s2 = x0 * x0 + x1 * x1 + x2 * x2 + x3 * x3;
#pragma unroll
  for (int o = 32; o >= 1; o >>= 1) {
    s1 += __shfl_xor(s1, o);
    s2 += __shfl_xor(s2, o);
  }
  const float mu = s1 * (1.f / 256.f);
  const float var = s2 * (1.f / 256.f) - mu * mu;
  const float rsig = rsqrtf(var + LN_EPS);
  const float4 g = *(const float4*)(gamma + c);
  const float4 bt = *(const float4*)(beta + c);
  float4 o;
  o.x = (x0 - mu) * rsig * g.x + bt.x;
  o.y = (x1 - mu) * rsig * g.y + bt.y;
  o.z = (x2 - mu) * rsig * g.z + bt.z;
  o.w = (x3 - mu) * rsig * g.w + bt.w;
  *(float4*)(y + (size_t)row * 256 + c) = o;
}

extern "C" void kernel_launch(void* const* d_in, const int* in_sizes, int n_in,
                              void* d_out, int out_size, void* d_ws, size_t ws_size,
                              hipStream_t stream) {
  const float* img_feat = (const float*)d_in[0];
  const unsigned char* img_mask = (const unsigned char*)d_in[2];
  const float* vratio = (const float*)d_in[3];
  const float* qf = (const float*)d_in[4];
  const float* qp = (const float*)d_in[5];
  const float* qpts = (const float*)d_in[6];
  const float* Wv = (const float*)d_in[7];
  const float* bv = (const float*)d_in[8];
  const float* Woff = (const float*)d_in[9];
  const float* boff = (const float*)d_in[10];
  const float* Wattn = (const float*)d_in[11];
  const float* battn = (const float*)d_in[12];
  const float* Wout = (const float*)d_in[13];
  const float* bout = (const float*)d_in[14];
  const float* gamma = (const float*)d_in[15];
  const float* beta = (const float*)d_in[16];

  char* ws = (char*)d_ws;
  bf16* V = (bf16*)ws;                                   // 22.3 MB (head-major; reused as upd)
  bf16* off = (bf16*)(ws + (size_t)NROW * 256 * 2);      // 22.3 MB (reused as samp)
  bf16* lg = (bf16*)(ws + (size_t)NROW * 256 * 4);       // 11.1 MB
  unsigned short* wbase =
      (unsigned short*)(ws + (size_t)NROW * 256 * 4 + (size_t)NROW * 128 * 2);
  unsigned short* WvT = wbase;              // 65536 shorts
  unsigned short* WcatT = WvT + 65536;      // 98304 shorts
  unsigned short* WoutT = WcatT + 98304;    // 65536 shorts -> ends 56.16MB (< proven 56.36MB)

  dim3 blk(256);
  k_trans<<<256, blk, 0, stream>>>(Wv, WvT, 256);
  k_trans<<<256, blk, 0, stream>>>(Woff, WcatT, 256);
  k_trans<<<128, blk, 0, stream>>>(Wattn, WcatT + 256 * 256, 128);
  k_trans<<<256, blk, 0, stream>>>(Wout, WoutT, 256);
  k_value<<<NROW / 64, blk, 0, stream>>>(img_feat, WvT, bv, img_mask, V);
  k_offattn<<<NROW / 64, blk, 0, stream>>>(qf, qp, WcatT, boff, battn, off, lg);
  k_sample<<<NROW / QB, blk, 0, stream>>>(V, off, lg, qpts, vratio,
                                          (unsigned short*)off /* samp alias */);
  k_upd<<<NROW / 64, blk, 0, stream>>>((const unsigned short*)off /* samp */, WoutT,
                                       bout, V /* = upd, dead */);
  k_ln<<<NROW / 4, blk, 0, stream>>>((const unsigned short*)V, qf, gamma, beta,
                                     (float*)d_out);
}